// Round 3
// baseline (3000.410 us; speedup 1.0000x reference)
//
#include <hip/hip_runtime.h>
#include <stdint.h>

typedef unsigned short u16;                                   // raw bf16 bits
typedef __bf16 v8bf __attribute__((ext_vector_type(8)));      // MFMA A/B frag
typedef float  v4f  __attribute__((ext_vector_type(4)));      // MFMA C/D frag

#define MFMA(a,b,c) __builtin_amdgcn_mfma_f32_16x16x32_bf16((a),(b),(c),0,0,0)

static __device__ __forceinline__ float bf2f(u16 u) {
    union { unsigned i; float f; } v; v.i = ((unsigned)u) << 16; return v.f;
}
static __device__ __forceinline__ u16 f2bf(float f) {         // RNE
    union { float f; unsigned i; } v; v.f = f;
    unsigned u = v.i;
    return (u16)((u + 0x7FFFu + ((u >> 16) & 1u)) >> 16);
}
// load 8 consecutive elements as a bf16 frag from fp32 OR bf16 storage
static __device__ __forceinline__ v8bf load8(const void* base, size_t off, bool f32) {
    union { u16 s[8]; v8bf v; } U;
    if (f32) {
        const float* p = (const float*)base + off;
        float4 a = *(const float4*)p;
        float4 b = *(const float4*)(p + 4);
        U.s[0] = f2bf(a.x); U.s[1] = f2bf(a.y); U.s[2] = f2bf(a.z); U.s[3] = f2bf(a.w);
        U.s[4] = f2bf(b.x); U.s[5] = f2bf(b.y); U.s[6] = f2bf(b.z); U.s[7] = f2bf(b.w);
    } else {
        U.v = *(const v8bf*)((const u16*)base + off);
    }
    return U.v;
}
static __device__ __forceinline__ float load1(const void* base, size_t off, bool f32) {
    return f32 ? ((const float*)base)[off] : bf2f(((const u16*)base)[off]);
}

// ---- Kernel 0: dtype probe (bf16 vs fp32 device buffers). bf16 N(0,1) data:
// low u16 of each u32 is a bf16 with exponent field in [110,140] ~always.
// fp32 data: low u16 = random mantissa bits -> only ~12% land in range. ----
__global__ void probe_kernel(const unsigned* __restrict__ x, int* __restrict__ flag) {
    if (threadIdx.x == 0 && blockIdx.x == 0) {
        int b16like = 0;
        for (int i = 0; i < 128; i++) {
            unsigned lo = x[i] & 0xFFFFu;
            int e = (lo >> 7) & 0xFF;
            if (e >= 110 && e <= 140) b16like++;
        }
        *flag = (b16like >= 64) ? 0 : 1;   // 1 => fp32 inputs
    }
}

// ---- Kernel 1: fused QKV + window cross-attention ----
// one wave per (s, b, h). grid (4096, 4). O (pre-projection, fp32) -> out.
__global__ __launch_bounds__(64) void fused_attn(
    const void* __restrict__ x, const void* __restrict__ y,
    const void* __restrict__ maskx, const void* __restrict__ masky,
    const void* __restrict__ wqkvx, const void* __restrict__ bqkvx,
    const void* __restrict__ wqkvy, const void* __restrict__ bqkvy,
    const void* __restrict__ rpb, const int* __restrict__ flag,
    float* __restrict__ out)
{
    const bool f32 = (*flag != 0);
    const int b = blockIdx.x >> 1;
    const int s = blockIdx.x & 1;
    const int h = blockIdx.y;
    const int lane = threadIdx.x;
    const int l15 = lane & 15, lg = lane >> 4;

    __shared__ u16 QL[125][40];     // Q head-slice [n][d]
    __shared__ u16 KL[125][40];     // K head-slice [n][d]
    __shared__ u16 VT[32][136];     // V^T head-slice [d][n]
    __shared__ u16 P[32][136];      // probs chunk (own buffer, no aliasing)

    const void* inS = s ? y : x;
    const void* inO = s ? x : y;
    const void* wS  = s ? wqkvy : wqkvx;
    const void* wO  = s ? wqkvx : wqkvy;
    const void* bS  = s ? bqkvy : bqkvx;
    const void* bO  = s ? bqkvx : bqkvy;
    const void* msk = s ? masky : maskx;

    const size_t inb = (size_t)b * (125 * 128);

    // ---------- Phase A: Q, K, V head-slices via MFMA ----------
    #pragma unroll
    for (int t = 0; t < 3; t++) {
        const void* src = t ? inO : inS;
        const void* wp  = t ? wO  : wS;
        const void* bp  = t ? bO  : bS;
        const int wrow = t * 128 + h * 32;

        v8bf bfr[2][4];
        float bv[2];
        #pragma unroll
        for (int nt = 0; nt < 2; nt++) {
            bv[nt] = load1(bp, wrow + nt * 16 + l15, f32);
            #pragma unroll
            for (int kk = 0; kk < 4; kk++)
                bfr[nt][kk] = load8(wp, (size_t)(wrow + nt * 16 + l15) * 128 + kk * 32 + lg * 8, f32);
        }
        #pragma unroll
        for (int mt = 0; mt < 8; mt++) {
            int ar = mt * 16 + l15; if (ar > 124) ar = 124;
            v8bf af[4];
            #pragma unroll
            for (int kk = 0; kk < 4; kk++)
                af[kk] = load8(src, inb + (size_t)ar * 128 + kk * 32 + lg * 8, f32);
            v4f a0 = {0.f,0.f,0.f,0.f}, a1 = {0.f,0.f,0.f,0.f};
            #pragma unroll
            for (int kk = 0; kk < 4; kk++) {
                a0 = MFMA(af[kk], bfr[0][kk], a0);
                a1 = MFMA(af[kk], bfr[1][kk], a1);
            }
            #pragma unroll
            for (int nt = 0; nt < 2; nt++) {
                const v4f acc = nt ? a1 : a0;
                const int col = nt * 16 + l15;
                #pragma unroll
                for (int ri = 0; ri < 4; ri++) {
                    const int wr = mt * 16 + lg * 4 + ri;      // D row = 4*(l>>4)+reg
                    if (wr < 125) {
                        const u16 val = f2bf(acc[ri] + bv[nt]);
                        if (t == 0)      QL[wr][col] = val;
                        else if (t == 1) KL[wr][col] = val;
                        else             VT[col][wr] = val;    // transpose V
                    }
                }
            }
        }
    }
    // zero V^T pad cols 125..127
    for (int z = lane; z < 96; z += 64) VT[z & 31][125 + (z >> 5)] = 0;
    __syncthreads();

    // ---------- resident K / V^T fragments ----------
    v8bf kf[8];
    #pragma unroll
    for (int jt = 0; jt < 8; jt++) {
        int r = jt * 16 + l15; if (r > 124) r = 124;
        kf[jt] = *(const v8bf*)&KL[r][lg * 8];
    }
    v8bf vf[2][4];
    #pragma unroll
    for (int n2 = 0; n2 < 2; n2++)
        #pragma unroll
        for (int kk = 0; kk < 4; kk++)
            vf[n2][kk] = *(const v8bf*)&VT[n2 * 16 + l15][kk * 32 + lg * 8];

    // rpb column-base per key tile: idx = prow + cb
    int cb[8];
    #pragma unroll
    for (int jt = 0; jt < 8; jt++) {
        int col = jt * 16 + l15; if (col > 124) col = 124;
        const int q0 = col / 25, rem = col - q0 * 25, q1 = rem / 5, q2 = rem - q1 * 5;
        cb[jt] = 364 - (q0 * 81 + q1 * 9 + q2);
    }
    const size_t mbase = (size_t)(b & 255) * 15625;
    const float scale = 0.17677669529663689f;   // 32^-0.5
    const v4f z4 = {0.f,0.f,0.f,0.f};

    // ---------- chunks of 32 query rows ----------
    for (int ch = 0; ch < 4; ch++) {
        v8bf qf[2];
        #pragma unroll
        for (int mt = 0; mt < 2; mt++) {
            int r = ch * 32 + mt * 16 + l15; if (r > 124) r = 124;
            qf[mt] = *(const v8bf*)&QL[r][lg * 8];
        }
        v4f acc[2][8];
        #pragma unroll
        for (int mt = 0; mt < 2; mt++)
            #pragma unroll
            for (int jt = 0; jt < 8; jt++) acc[mt][jt] = z4;
        #pragma unroll
        for (int jt = 0; jt < 8; jt++)
            #pragma unroll
            for (int mt = 0; mt < 2; mt++)
                acc[mt][jt] = MFMA(qf[mt], kf[jt], acc[mt][jt]);

        float rinv[2][4];
        #pragma unroll
        for (int mt = 0; mt < 2; mt++) {
            #pragma unroll
            for (int ri = 0; ri < 4; ri++) {
                const int row = ch * 32 + mt * 16 + lg * 4 + ri;
                const bool rv = row < 125;
                int prow = 0; size_t moff = 0;
                if (rv) {
                    const int p0 = row / 25, rem = row - p0 * 25, p1 = rem / 5, p2 = rem - p1 * 5;
                    prow = p0 * 81 + p1 * 9 + p2;
                    moff = mbase + (size_t)row * 125;
                }
                #pragma unroll
                for (int jt = 0; jt < 8; jt++) {
                    const int col = jt * 16 + l15;
                    float vv = -1e30f;
                    if (rv && col < 125)
                        vv = acc[mt][jt][ri] * scale
                           + load1(rpb, (size_t)(prow + cb[jt]) * 4 + h, f32)
                           + load1(msk, moff + col, f32);
                    acc[mt][jt][ri] = vv;
                }
                float mx = acc[mt][0][ri];
                #pragma unroll
                for (int jt = 1; jt < 8; jt++) mx = fmaxf(mx, acc[mt][jt][ri]);
                mx = fmaxf(mx, __shfl_xor(mx, 1));
                mx = fmaxf(mx, __shfl_xor(mx, 2));
                mx = fmaxf(mx, __shfl_xor(mx, 4));
                mx = fmaxf(mx, __shfl_xor(mx, 8));
                float sum = 0.f;
                #pragma unroll
                for (int jt = 0; jt < 8; jt++) {
                    const float pv = __expf(acc[mt][jt][ri] - mx);
                    acc[mt][jt][ri] = pv; sum += pv;
                }
                sum += __shfl_xor(sum, 1);
                sum += __shfl_xor(sum, 2);
                sum += __shfl_xor(sum, 4);
                sum += __shfl_xor(sum, 8);
                rinv[mt][ri] = 1.0f / sum;      // folded into O
            }
        }

        // P (D-layout) -> LDS (A-layout)
        __syncthreads();
        #pragma unroll
        for (int mt = 0; mt < 2; mt++)
            #pragma unroll
            for (int jt = 0; jt < 8; jt++)
                #pragma unroll
                for (int ri = 0; ri < 4; ri++)
                    P[mt * 16 + lg * 4 + ri][jt * 16 + l15] = f2bf(acc[mt][jt][ri]);
        __syncthreads();

        v4f o[2][2];
        #pragma unroll
        for (int mt = 0; mt < 2; mt++)
            #pragma unroll
            for (int n2 = 0; n2 < 2; n2++) o[mt][n2] = z4;
        #pragma unroll
        for (int mt = 0; mt < 2; mt++) {
            v8bf pa[4];
            #pragma unroll
            for (int kk = 0; kk < 4; kk++)
                pa[kk] = *(const v8bf*)&P[mt * 16 + l15][kk * 32 + lg * 8];
            #pragma unroll
            for (int n2 = 0; n2 < 2; n2++)
                #pragma unroll
                for (int kk = 0; kk < 4; kk++)
                    o[mt][n2] = MFMA(pa[kk], vf[n2][kk], o[mt][n2]);
        }

        #pragma unroll
        for (int mt = 0; mt < 2; mt++)
            #pragma unroll
            for (int n2 = 0; n2 < 2; n2++)
                #pragma unroll
                for (int ri = 0; ri < 4; ri++) {
                    const int row = ch * 32 + mt * 16 + lg * 4 + ri;
                    if (row < 125)
                        out[((size_t)s * 256000 + (size_t)b * 125 + row) * 128
                            + h * 32 + n2 * 16 + l15] = o[mt][n2][ri] * rinv[mt][ri];
                }
    }
}

// ---- Kernel 2: output projection, in place on fp32 d_out ----
__global__ __launch_bounds__(256) void proj_kernel(
    const void* __restrict__ wpx, const void* __restrict__ bpx,
    const void* __restrict__ wpy, const void* __restrict__ bpy,
    const int* __restrict__ flag, float* io)
{
    const bool f32 = (*flag != 0);
    const int s  = blockIdx.y;
    const int bm = blockIdx.x;
    const void* W    = s ? wpy : wpx;
    const void* bias = s ? bpy : bpx;
    float* A = io + (size_t)s * 32768000;
    const int tid = threadIdx.x, lane = tid & 63, wv = tid >> 6;
    const int l15 = lane & 15, lg = lane >> 4;

    __shared__ u16 Wl[128][136];
    for (int i = tid * 8; i < 16384; i += 2048)
        *(v8bf*)&Wl[i >> 7][i & 127] = load8(W, i, f32);
    __syncthreads();

    const int mbase = bm * 64 + wv * 16;
    v4f acc[8];
    const v4f z4 = {0.f,0.f,0.f,0.f};
    #pragma unroll
    for (int nt = 0; nt < 8; nt++) acc[nt] = z4;

    const float* Ar = A + (size_t)(mbase + l15) * 128;
    v8bf afr[4];
    #pragma unroll
    for (int kk = 0; kk < 4; kk++) {
        union { u16 sI[8]; v8bf v; } U;
        float4 fa = *(const float4*)(Ar + kk * 32 + lg * 8);
        float4 fb = *(const float4*)(Ar + kk * 32 + lg * 8 + 4);
        U.sI[0] = f2bf(fa.x); U.sI[1] = f2bf(fa.y); U.sI[2] = f2bf(fa.z); U.sI[3] = f2bf(fa.w);
        U.sI[4] = f2bf(fb.x); U.sI[5] = f2bf(fb.y); U.sI[6] = f2bf(fb.z); U.sI[7] = f2bf(fb.w);
        afr[kk] = U.v;
    }
    #pragma unroll
    for (int kk = 0; kk < 4; kk++)
        #pragma unroll
        for (int nt = 0; nt < 8; nt++)
            acc[nt] = MFMA(afr[kk], *(const v8bf*)&Wl[nt * 16 + l15][kk * 32 + lg * 8], acc[nt]);

    #pragma unroll
    for (int nt = 0; nt < 8; nt++) {
        const int c = nt * 16 + l15;
        const float bv = load1(bias, c, f32);
        #pragma unroll
        for (int ri = 0; ri < 4; ri++)
            A[(size_t)(mbase + lg * 4 + ri) * 128 + c] = acc[nt][ri] + bv;
    }
}

extern "C" void kernel_launch(void* const* d_in, const int* in_sizes, int n_in,
                              void* d_out, int out_size, void* d_ws, size_t ws_size,
                              hipStream_t stream) {
    const void* x     = d_in[0];
    const void* y     = d_in[1];
    const void* maskx = d_in[2];
    const void* masky = d_in[3];
    const void* wqx   = d_in[4];
    const void* bqx   = d_in[5];
    const void* wqy   = d_in[6];
    const void* bqy   = d_in[7];
    const void* wpx   = d_in[8];
    const void* bpx   = d_in[9];
    const void* wpy   = d_in[10];
    const void* bpy   = d_in[11];
    const void* rpb   = d_in[12];

    int* flag = (int*)d_ws;                       // 4 bytes of scratch total

    probe_kernel<<<1, 64, 0, stream>>>((const unsigned*)x, flag);
    fused_attn<<<dim3(4096, 4), 64, 0, stream>>>(x, y, maskx, masky,
                                                 wqx, bqx, wqy, bqy,
                                                 rpb, flag, (float*)d_out);
    proj_kernel<<<dim3(4000, 2), 256, 0, stream>>>(wpx, bpx, wpy, bpy,
                                                   flag, (float*)d_out);
}

// Round 4
// 2625.070 us; speedup vs baseline: 1.1430x; 1.1430x over previous
//
#include <hip/hip_runtime.h>
#include <stdint.h>

typedef unsigned short u16;                                   // raw bf16 bits
typedef __bf16 v8bf __attribute__((ext_vector_type(8)));      // MFMA A/B frag
typedef float  v4f  __attribute__((ext_vector_type(4)));      // MFMA C/D frag

#define MFMA(a,b,c) __builtin_amdgcn_mfma_f32_16x16x32_bf16((a),(b),(c),0,0,0)

static __device__ __forceinline__ float bf2f(u16 u) {
    union { unsigned i; float f; } v; v.i = ((unsigned)u) << 16; return v.f;
}
static __device__ __forceinline__ u16 f2bf(float f) {         // RNE
    union { float f; unsigned i; } v; v.f = f;
    unsigned u = v.i;
    return (u16)((u + 0x7FFFu + ((u >> 16) & 1u)) >> 16);
}
// load 8 consecutive elements as a bf16 frag from fp32 OR bf16 storage
static __device__ __forceinline__ v8bf load8(const void* base, size_t off, bool f32) {
    union { u16 s[8]; v8bf v; } U;
    if (f32) {
        const float* p = (const float*)base + off;
        float4 a = *(const float4*)p;
        float4 b = *(const float4*)(p + 4);
        U.s[0] = f2bf(a.x); U.s[1] = f2bf(a.y); U.s[2] = f2bf(a.z); U.s[3] = f2bf(a.w);
        U.s[4] = f2bf(b.x); U.s[5] = f2bf(b.y); U.s[6] = f2bf(b.z); U.s[7] = f2bf(b.w);
    } else {
        U.v = *(const v8bf*)((const u16*)base + off);
    }
    return U.v;
}
static __device__ __forceinline__ float load1(const void* base, size_t off, bool f32) {
    return f32 ? ((const float*)base)[off] : bf2f(((const u16*)base)[off]);
}

// ---- dtype probe: bf16 vs fp32 device buffers ----
__global__ void probe_kernel(const unsigned* __restrict__ x, int* __restrict__ flag) {
    if (threadIdx.x == 0 && blockIdx.x == 0) {
        int b16like = 0;
        for (int i = 0; i < 128; i++) {
            unsigned lo = x[i] & 0xFFFFu;
            int e = (lo >> 7) & 0xFF;
            if (e >= 110 && e <= 140) b16like++;
        }
        *flag = (b16like >= 64) ? 0 : 1;   // 1 => fp32 inputs
    }
}

// =================== FAST PATH (uses workspace) ===================

// ---- K1: rpbT[h][col][row(pad 128)] fp32, 256KB, L2-hot in attn ----
__global__ __launch_bounds__(256) void rpbt_kernel(
    const void* __restrict__ rpb, const int* __restrict__ flag,
    float* __restrict__ rpbT)
{
    const bool f32 = (*flag != 0);
    const int h = blockIdx.x;
    for (int i = threadIdx.x; i < 16000; i += 256) {
        const int col = i >> 7, row = i & 127;
        float v = 0.f;
        if (row < 125) {
            const int p0 = row / 25, prem = row - p0 * 25, p1 = prem / 5, p2 = prem - p1 * 5;
            const int q0 = col / 25, qrem = col - q0 * 25, q1 = qrem / 5, q2 = qrem - q1 * 5;
            const int idx = (p0 - q0 + 4) * 81 + (p1 - q1 + 4) * 9 + (p2 - q2 + 4);
            v = load1(rpb, (size_t)idx * 4 + h, f32);
        }
        rpbT[(size_t)h * 16000 + i] = v;
    }
}

// ---- K2: QKV GEMM. q,k -> [s][b][h][n][32] bf16 ; v -> [s][b][h][d][128] bf16 (transposed) ----
// grid (4000, 6, 2) block 256 (4 waves, each 32x32 of a 64x64 tile)
__global__ __launch_bounds__(256) void qkv_kernel(
    const void* __restrict__ x, const void* __restrict__ y,
    const void* __restrict__ wqkvx, const void* __restrict__ bqkvx,
    const void* __restrict__ wqkvy, const void* __restrict__ bqkvy,
    const int* __restrict__ flag,
    u16* __restrict__ q, u16* __restrict__ k, u16* __restrict__ vT)
{
    const bool f32 = (*flag != 0);
    const int s = blockIdx.z;
    const void* A  = s ? y : x;
    const void* W  = s ? wqkvy : wqkvx;
    const void* bi = s ? bqkvy : bqkvx;
    const int bm = blockIdx.x, bn = blockIdx.y;
    const int tid = threadIdx.x, lane = tid & 63, wv = tid >> 6;
    const int wrow = (wv >> 1) * 32, wcol = (wv & 1) * 32;
    const int l15 = lane & 15, lg = lane >> 4;

    __shared__ u16 Wl[64][136];
    {
        const int r = tid >> 2, k0 = (tid & 3) * 32;
        #pragma unroll
        for (int i = 0; i < 4; i++)
            *(v8bf*)&Wl[r][k0 + i * 8] = load8(W, (size_t)(bn * 64 + r) * 128 + k0 + i * 8, f32);
    }
    __syncthreads();

    const int mbase = bm * 64 + wrow;
    v8bf af[2][4];
    #pragma unroll
    for (int mt = 0; mt < 2; mt++)
        #pragma unroll
        for (int kk = 0; kk < 4; kk++)
            af[mt][kk] = load8(A, (size_t)(mbase + mt * 16 + l15) * 128 + kk * 32 + lg * 8, f32);

    v8bf bfr[2][4];
    #pragma unroll
    for (int nt = 0; nt < 2; nt++)
        #pragma unroll
        for (int kk = 0; kk < 4; kk++)
            bfr[nt][kk] = *(const v8bf*)&Wl[wcol + nt * 16 + l15][kk * 32 + lg * 8];

    v4f acc[2][2];
    const v4f z4 = {0.f,0.f,0.f,0.f};
    #pragma unroll
    for (int mt = 0; mt < 2; mt++)
        #pragma unroll
        for (int nt = 0; nt < 2; nt++) acc[mt][nt] = z4;
    #pragma unroll
    for (int kk = 0; kk < 4; kk++)
        #pragma unroll
        for (int mt = 0; mt < 2; mt++)
            #pragma unroll
            for (int nt = 0; nt < 2; nt++)
                acc[mt][nt] = MFMA(af[mt][kk], bfr[nt][kk], acc[mt][nt]);

    #pragma unroll
    for (int mt = 0; mt < 2; mt++) {
        #pragma unroll
        for (int nt = 0; nt < 2; nt++) {
            const int cbase = bn * 64 + wcol + nt * 16;   // within one (t,h,d16) group
            const int three = cbase >> 7;
            const int h     = (cbase >> 5) & 3;
            const int d     = (cbase & 31) + l15;
            const float bv  = load1(bi, cbase + l15, f32);
            #pragma unroll
            for (int ri = 0; ri < 4; ri++) {
                const int m = mbase + mt * 16 + lg * 4 + ri;   // D row = 4*(l>>4)+reg
                const int b = m / 125;
                const int n = m - b * 125;
                const u16 vb16 = f2bf(acc[mt][nt][ri] + bv);
                const size_t hb = (size_t)(s * 2048 + b) * 4 + h;
                if (three == 0)      q[hb * 4000 + n * 32 + d] = vb16;
                else if (three == 1) k[hb * 4000 + n * 32 + d] = vb16;
                else                 vT[hb * 4096 + (size_t)d * 128 + n] = vb16;
            }
        }
    }
}

// ---- K3: window cross-attention. one wave per (s,b,h); LDS = P only (8.7KB) ----
// block mapping: 16 consecutive blocks share the same (w,h) mask/rpb slice.
__global__ __launch_bounds__(64) void attn_kernel(
    const u16* __restrict__ q, const u16* __restrict__ k, const u16* __restrict__ vT,
    const void* __restrict__ maskx, const void* __restrict__ masky,
    const float* __restrict__ rpbT, const int* __restrict__ flag,
    float* __restrict__ out)
{
    const bool f32 = (*flag != 0);
    const int j = blockIdx.x;
    const int rep = j & 15, h = (j >> 4) & 3, w = j >> 6;
    const int s = rep & 1, b = (rep >> 1) * 256 + w;
    const int lane = threadIdx.x, l15 = lane & 15, lg = lane >> 4;

    __shared__ u16 P[32][136];

    const u16* qb = q  + ((size_t)(s * 2048 + b) * 4 + h) * 4000;
    const u16* kb = k  + ((size_t)((1 - s) * 2048 + b) * 4 + h) * 4000;
    const u16* vb = vT + ((size_t)((1 - s) * 2048 + b) * 4 + h) * 4096;
    const void* msk = s ? masky : maskx;
    const size_t mbase = (size_t)w * 15625;
    const float* rT = rpbT + (size_t)h * 16000;

    v8bf kf[8];
    #pragma unroll
    for (int jt = 0; jt < 8; jt++) {
        int r = jt * 16 + l15; if (r > 124) r = 124;
        kf[jt] = *(const v8bf*)(kb + r * 32 + lg * 8);
    }
    v8bf vf[2][4];
    #pragma unroll
    for (int n2 = 0; n2 < 2; n2++)
        #pragma unroll
        for (int kk = 0; kk < 4; kk++)
            vf[n2][kk] = *(const v8bf*)(vb + (n2 * 16 + l15) * 128 + kk * 32 + lg * 8);

    int colc[8];
    #pragma unroll
    for (int jt = 0; jt < 8; jt++) {
        int c = jt * 16 + l15; if (c > 124) c = 124;
        colc[jt] = c;
    }
    const float scale = 0.17677669529663689f;   // 32^-0.5
    const v4f z4 = {0.f,0.f,0.f,0.f};

    for (int ch = 0; ch < 4; ch++) {
        v8bf qf[2];
        #pragma unroll
        for (int mt = 0; mt < 2; mt++) {
            int r = ch * 32 + mt * 16 + l15; if (r > 124) r = 124;
            qf[mt] = *(const v8bf*)(qb + r * 32 + lg * 8);
        }
        v4f acc[2][8];
        #pragma unroll
        for (int mt = 0; mt < 2; mt++)
            #pragma unroll
            for (int jt = 0; jt < 8; jt++) acc[mt][jt] = z4;
        #pragma unroll
        for (int jt = 0; jt < 8; jt++)
            #pragma unroll
            for (int mt = 0; mt < 2; mt++)
                acc[mt][jt] = MFMA(qf[mt], kf[jt], acc[mt][jt]);

        float rinv[2][4];
        #pragma unroll
        for (int mt = 0; mt < 2; mt++) {
            const int rowb = ch * 32 + mt * 16 + lg * 4;
            float4 c4[8];                       // rpb bias, D-layout float4 per key tile
            #pragma unroll
            for (int jt = 0; jt < 8; jt++)
                c4[jt] = *(const float4*)(rT + colc[jt] * 128 + rowb);
            #pragma unroll
            for (int ri = 0; ri < 4; ri++) {
                const int row = rowb + ri;
                const bool rv = row < 125;
                const size_t moff = mbase + (size_t)(rv ? row : 0) * 125;
                #pragma unroll
                for (int jt = 0; jt < 8; jt++) {
                    const int col = jt * 16 + l15;
                    float vv = -1e30f;
                    if (rv && col < 125) {
                        const float rb = (&c4[jt].x)[ri];
                        vv = acc[mt][jt][ri] * scale + rb + load1(msk, moff + col, f32);
                    }
                    acc[mt][jt][ri] = vv;
                }
                float mx = acc[mt][0][ri];
                #pragma unroll
                for (int jt = 1; jt < 8; jt++) mx = fmaxf(mx, acc[mt][jt][ri]);
                mx = fmaxf(mx, __shfl_xor(mx, 1));
                mx = fmaxf(mx, __shfl_xor(mx, 2));
                mx = fmaxf(mx, __shfl_xor(mx, 4));
                mx = fmaxf(mx, __shfl_xor(mx, 8));
                float sum = 0.f;
                #pragma unroll
                for (int jt = 0; jt < 8; jt++) {
                    const float pv = __expf(acc[mt][jt][ri] - mx);
                    acc[mt][jt][ri] = pv; sum += pv;
                }
                sum += __shfl_xor(sum, 1);
                sum += __shfl_xor(sum, 2);
                sum += __shfl_xor(sum, 4);
                sum += __shfl_xor(sum, 8);
                rinv[mt][ri] = 1.0f / sum;      // folded into O
            }
        }

        // P (D-layout) -> LDS (A-layout); in-wave ordering, no barrier needed
        #pragma unroll
        for (int mt = 0; mt < 2; mt++)
            #pragma unroll
            for (int jt = 0; jt < 8; jt++)
                #pragma unroll
                for (int ri = 0; ri < 4; ri++)
                    P[mt * 16 + lg * 4 + ri][jt * 16 + l15] = f2bf(acc[mt][jt][ri]);

        v4f o[2][2];
        #pragma unroll
        for (int mt = 0; mt < 2; mt++)
            #pragma unroll
            for (int n2 = 0; n2 < 2; n2++) o[mt][n2] = z4;
        #pragma unroll
        for (int mt = 0; mt < 2; mt++) {
            v8bf pa[4];
            #pragma unroll
            for (int kk = 0; kk < 4; kk++)
                pa[kk] = *(const v8bf*)&P[mt * 16 + l15][kk * 32 + lg * 8];
            #pragma unroll
            for (int n2 = 0; n2 < 2; n2++)
                #pragma unroll
                for (int kk = 0; kk < 4; kk++)
                    o[mt][n2] = MFMA(pa[kk], vf[n2][kk], o[mt][n2]);
        }

        #pragma unroll
        for (int mt = 0; mt < 2; mt++)
            #pragma unroll
            for (int n2 = 0; n2 < 2; n2++)
                #pragma unroll
                for (int ri = 0; ri < 4; ri++) {
                    const int row = ch * 32 + mt * 16 + lg * 4 + ri;
                    if (row < 125)
                        out[((size_t)s * 256000 + (size_t)b * 125 + row) * 128
                            + h * 32 + n2 * 16 + l15] = o[mt][n2][ri] * rinv[mt][ri];
                }
    }
}

// =================== SLOW PATH (round-3 validated fallback) ===================

__global__ __launch_bounds__(64) void fused_attn(
    const void* __restrict__ x, const void* __restrict__ y,
    const void* __restrict__ maskx, const void* __restrict__ masky,
    const void* __restrict__ wqkvx, const void* __restrict__ bqkvx,
    const void* __restrict__ wqkvy, const void* __restrict__ bqkvy,
    const void* __restrict__ rpb, const int* __restrict__ flag,
    float* __restrict__ out)
{
    const bool f32 = (*flag != 0);
    const int b = blockIdx.x >> 1;
    const int s = blockIdx.x & 1;
    const int h = blockIdx.y;
    const int lane = threadIdx.x;
    const int l15 = lane & 15, lg = lane >> 4;

    __shared__ u16 QL[125][40];
    __shared__ u16 KL[125][40];
    __shared__ u16 VT[32][136];
    __shared__ u16 P[32][136];

    const void* inS = s ? y : x;
    const void* inO = s ? x : y;
    const void* wS  = s ? wqkvy : wqkvx;
    const void* wO  = s ? wqkvx : wqkvy;
    const void* bS  = s ? bqkvy : bqkvx;
    const void* bO  = s ? bqkvx : bqkvy;
    const void* msk = s ? masky : maskx;

    const size_t inb = (size_t)b * (125 * 128);

    #pragma unroll
    for (int t = 0; t < 3; t++) {
        const void* src = t ? inO : inS;
        const void* wp  = t ? wO  : wS;
        const void* bp  = t ? bO  : bS;
        const int wrow = t * 128 + h * 32;

        v8bf bfr[2][4];
        float bv[2];
        #pragma unroll
        for (int nt = 0; nt < 2; nt++) {
            bv[nt] = load1(bp, wrow + nt * 16 + l15, f32);
            #pragma unroll
            for (int kk = 0; kk < 4; kk++)
                bfr[nt][kk] = load8(wp, (size_t)(wrow + nt * 16 + l15) * 128 + kk * 32 + lg * 8, f32);
        }
        #pragma unroll
        for (int mt = 0; mt < 8; mt++) {
            int ar = mt * 16 + l15; if (ar > 124) ar = 124;
            v8bf af[4];
            #pragma unroll
            for (int kk = 0; kk < 4; kk++)
                af[kk] = load8(src, inb + (size_t)ar * 128 + kk * 32 + lg * 8, f32);
            v4f a0 = {0.f,0.f,0.f,0.f}, a1 = {0.f,0.f,0.f,0.f};
            #pragma unroll
            for (int kk = 0; kk < 4; kk++) {
                a0 = MFMA(af[kk], bfr[0][kk], a0);
                a1 = MFMA(af[kk], bfr[1][kk], a1);
            }
            #pragma unroll
            for (int nt = 0; nt < 2; nt++) {
                const v4f acc = nt ? a1 : a0;
                const int col = nt * 16 + l15;
                #pragma unroll
                for (int ri = 0; ri < 4; ri++) {
                    const int wr = mt * 16 + lg * 4 + ri;
                    if (wr < 125) {
                        const u16 val = f2bf(acc[ri] + bv[nt]);
                        if (t == 0)      QL[wr][col] = val;
                        else if (t == 1) KL[wr][col] = val;
                        else             VT[col][wr] = val;
                    }
                }
            }
        }
    }
    for (int z = lane; z < 96; z += 64) VT[z & 31][125 + (z >> 5)] = 0;
    __syncthreads();

    v8bf kf[8];
    #pragma unroll
    for (int jt = 0; jt < 8; jt++) {
        int r = jt * 16 + l15; if (r > 124) r = 124;
        kf[jt] = *(const v8bf*)&KL[r][lg * 8];
    }
    v8bf vf[2][4];
    #pragma unroll
    for (int n2 = 0; n2 < 2; n2++)
        #pragma unroll
        for (int kk = 0; kk < 4; kk++)
            vf[n2][kk] = *(const v8bf*)&VT[n2 * 16 + l15][kk * 32 + lg * 8];

    int cb[8];
    #pragma unroll
    for (int jt = 0; jt < 8; jt++) {
        int col = jt * 16 + l15; if (col > 124) col = 124;
        const int q0 = col / 25, rem = col - q0 * 25, q1 = rem / 5, q2 = rem - q1 * 5;
        cb[jt] = 364 - (q0 * 81 + q1 * 9 + q2);
    }
    const size_t mbase = (size_t)(b & 255) * 15625;
    const float scale = 0.17677669529663689f;
    const v4f z4 = {0.f,0.f,0.f,0.f};

    for (int ch = 0; ch < 4; ch++) {
        v8bf qf[2];
        #pragma unroll
        for (int mt = 0; mt < 2; mt++) {
            int r = ch * 32 + mt * 16 + l15; if (r > 124) r = 124;
            qf[mt] = *(const v8bf*)&QL[r][lg * 8];
        }
        v4f acc[2][8];
        #pragma unroll
        for (int mt = 0; mt < 2; mt++)
            #pragma unroll
            for (int jt = 0; jt < 8; jt++) acc[mt][jt] = z4;
        #pragma unroll
        for (int jt = 0; jt < 8; jt++)
            #pragma unroll
            for (int mt = 0; mt < 2; mt++)
                acc[mt][jt] = MFMA(qf[mt], kf[jt], acc[mt][jt]);

        float rinv[2][4];
        #pragma unroll
        for (int mt = 0; mt < 2; mt++) {
            #pragma unroll
            for (int ri = 0; ri < 4; ri++) {
                const int row = ch * 32 + mt * 16 + lg * 4 + ri;
                const bool rv = row < 125;
                int prow = 0; size_t moff = 0;
                if (rv) {
                    const int p0 = row / 25, rem = row - p0 * 25, p1 = rem / 5, p2 = rem - p1 * 5;
                    prow = p0 * 81 + p1 * 9 + p2;
                    moff = mbase + (size_t)row * 125;
                }
                #pragma unroll
                for (int jt = 0; jt < 8; jt++) {
                    const int col = jt * 16 + l15;
                    float vv = -1e30f;
                    if (rv && col < 125)
                        vv = acc[mt][jt][ri] * scale
                           + load1(rpb, (size_t)(prow + cb[jt]) * 4 + h, f32)
                           + load1(msk, moff + col, f32);
                    acc[mt][jt][ri] = vv;
                }
                float mx = acc[mt][0][ri];
                #pragma unroll
                for (int jt = 1; jt < 8; jt++) mx = fmaxf(mx, acc[mt][jt][ri]);
                mx = fmaxf(mx, __shfl_xor(mx, 1));
                mx = fmaxf(mx, __shfl_xor(mx, 2));
                mx = fmaxf(mx, __shfl_xor(mx, 4));
                mx = fmaxf(mx, __shfl_xor(mx, 8));
                float sum = 0.f;
                #pragma unroll
                for (int jt = 0; jt < 8; jt++) {
                    const float pv = __expf(acc[mt][jt][ri] - mx);
                    acc[mt][jt][ri] = pv; sum += pv;
                }
                sum += __shfl_xor(sum, 1);
                sum += __shfl_xor(sum, 2);
                sum += __shfl_xor(sum, 4);
                sum += __shfl_xor(sum, 8);
                rinv[mt][ri] = 1.0f / sum;
            }
        }

        __syncthreads();
        #pragma unroll
        for (int mt = 0; mt < 2; mt++)
            #pragma unroll
            for (int jt = 0; jt < 8; jt++)
                #pragma unroll
                for (int ri = 0; ri < 4; ri++)
                    P[mt * 16 + lg * 4 + ri][jt * 16 + l15] = f2bf(acc[mt][jt][ri]);
        __syncthreads();

        v4f o[2][2];
        #pragma unroll
        for (int mt = 0; mt < 2; mt++)
            #pragma unroll
            for (int n2 = 0; n2 < 2; n2++) o[mt][n2] = z4;
        #pragma unroll
        for (int mt = 0; mt < 2; mt++) {
            v8bf pa[4];
            #pragma unroll
            for (int kk = 0; kk < 4; kk++)
                pa[kk] = *(const v8bf*)&P[mt * 16 + l15][kk * 32 + lg * 8];
            #pragma unroll
            for (int n2 = 0; n2 < 2; n2++)
                #pragma unroll
                for (int kk = 0; kk < 4; kk++)
                    o[mt][n2] = MFMA(pa[kk], vf[n2][kk], o[mt][n2]);
        }

        #pragma unroll
        for (int mt = 0; mt < 2; mt++)
            #pragma unroll
            for (int n2 = 0; n2 < 2; n2++)
                #pragma unroll
                for (int ri = 0; ri < 4; ri++) {
                    const int row = ch * 32 + mt * 16 + lg * 4 + ri;
                    if (row < 125)
                        out[((size_t)s * 256000 + (size_t)b * 125 + row) * 128
                            + h * 32 + n2 * 16 + l15] = o[mt][n2][ri] * rinv[mt][ri];
                }
    }
}

// ---- output projection, in place on fp32 d_out (shared by both paths) ----
__global__ __launch_bounds__(256) void proj_kernel(
    const void* __restrict__ wpx, const void* __restrict__ bpx,
    const void* __restrict__ wpy, const void* __restrict__ bpy,
    const int* __restrict__ flag, float* io)
{
    const bool f32 = (*flag != 0);
    const int s  = blockIdx.y;
    const int bm = blockIdx.x;
    const void* W    = s ? wpy : wpx;
    const void* bias = s ? bpy : bpx;
    float* A = io + (size_t)s * 32768000;
    const int tid = threadIdx.x, lane = tid & 63, wv = tid >> 6;
    const int l15 = lane & 15, lg = lane >> 4;

    __shared__ u16 Wl[128][136];
    for (int i = tid * 8; i < 16384; i += 2048)
        *(v8bf*)&Wl[i >> 7][i & 127] = load8(W, i, f32);
    __syncthreads();

    const int mbase = bm * 64 + wv * 16;
    v4f acc[8];
    const v4f z4 = {0.f,0.f,0.f,0.f};
    #pragma unroll
    for (int nt = 0; nt < 8; nt++) acc[nt] = z4;

    const float* Ar = A + (size_t)(mbase + l15) * 128;
    v8bf afr[4];
    #pragma unroll
    for (int kk = 0; kk < 4; kk++) {
        union { u16 sI[8]; v8bf v; } U;
        float4 fa = *(const float4*)(Ar + kk * 32 + lg * 8);
        float4 fb = *(const float4*)(Ar + kk * 32 + lg * 8 + 4);
        U.sI[0] = f2bf(fa.x); U.sI[1] = f2bf(fa.y); U.sI[2] = f2bf(fa.z); U.sI[3] = f2bf(fa.w);
        U.sI[4] = f2bf(fb.x); U.sI[5] = f2bf(fb.y); U.sI[6] = f2bf(fb.z); U.sI[7] = f2bf(fb.w);
        afr[kk] = U.v;
    }
    #pragma unroll
    for (int kk = 0; kk < 4; kk++)
        #pragma unroll
        for (int nt = 0; nt < 8; nt++)
            acc[nt] = MFMA(afr[kk], *(const v8bf*)&Wl[nt * 16 + l15][kk * 32 + lg * 8], acc[nt]);

    #pragma unroll
    for (int nt = 0; nt < 8; nt++) {
        const int c = nt * 16 + l15;
        const float bv = load1(bias, c, f32);
        #pragma unroll
        for (int ri = 0; ri < 4; ri++)
            A[(size_t)(mbase + lg * 4 + ri) * 128 + c] = acc[nt][ri] + bv;
    }
}

extern "C" void kernel_launch(void* const* d_in, const int* in_sizes, int n_in,
                              void* d_out, int out_size, void* d_ws, size_t ws_size,
                              hipStream_t stream) {
    const void* x     = d_in[0];
    const void* y     = d_in[1];
    const void* maskx = d_in[2];
    const void* masky = d_in[3];
    const void* wqx   = d_in[4];
    const void* bqx   = d_in[5];
    const void* wqy   = d_in[6];
    const void* bqy   = d_in[7];
    const void* wpx   = d_in[8];
    const void* bpx   = d_in[9];
    const void* wpy   = d_in[10];
    const void* bpy   = d_in[11];
    const void* rpb   = d_in[12];

    // fast-path workspace layout (bytes)
    const size_t OFF_RPBT = 0;                       // 64000 f32   = 256,000 B
    const size_t OFF_Q    = 256000;                  // 65.536M bf16 = 131,072,000 B
    const size_t OFF_K    = OFF_Q + 131072000;
    const size_t OFF_VT   = OFF_K + 131072000;       // 67.109M bf16 = 134,217,728 B
    const size_t OFF_FLAG = OFF_VT + 134217728;
    const size_t NEED     = OFF_FLAG + 4;            // 396,617,732 B

    if (ws_size >= NEED) {
        float* rpbT = (float*)((char*)d_ws + OFF_RPBT);
        u16*   q    = (u16*)((char*)d_ws + OFF_Q);
        u16*   k    = (u16*)((char*)d_ws + OFF_K);
        u16*   vT   = (u16*)((char*)d_ws + OFF_VT);
        int*   flag = (int*)((char*)d_ws + OFF_FLAG);

        probe_kernel<<<1, 64, 0, stream>>>((const unsigned*)x, flag);
        rpbt_kernel<<<4, 256, 0, stream>>>(rpb, flag, rpbT);
        qkv_kernel<<<dim3(4000, 6, 2), 256, 0, stream>>>(x, y, wqx, bqx, wqy, bqy,
                                                         flag, q, k, vT);
        attn_kernel<<<16384, 64, 0, stream>>>(q, k, vT, maskx, masky, rpbT, flag,
                                              (float*)d_out);
        proj_kernel<<<dim3(4000, 2), 256, 0, stream>>>(wpx, bpx, wpy, bpy,
                                                       flag, (float*)d_out);
    } else {
        int* flag = (int*)d_ws;
        probe_kernel<<<1, 64, 0, stream>>>((const unsigned*)x, flag);
        fused_attn<<<dim3(4096, 4), 64, 0, stream>>>(x, y, maskx, masky,
                                                     wqx, bqx, wqy, bqy,
                                                     rpb, flag, (float*)d_out);
        proj_kernel<<<dim3(4000, 2), 256, 0, stream>>>(wpx, bpx, wpy, bpy,
                                                       flag, (float*)d_out);
    }
}

// Round 5
// 1200.952 us; speedup vs baseline: 2.4984x; 2.1858x over previous
//
#include <hip/hip_runtime.h>
#include <stdint.h>

typedef unsigned short u16;                                   // raw bf16 bits
typedef __bf16 v8bf __attribute__((ext_vector_type(8)));      // MFMA A/B frag
typedef float  v4f  __attribute__((ext_vector_type(4)));      // MFMA C/D frag
typedef u16    u16x4 __attribute__((ext_vector_type(4)));

#define MFMA(a,b,c) __builtin_amdgcn_mfma_f32_16x16x32_bf16((a),(b),(c),0,0,0)

static __device__ __forceinline__ float bf2f(u16 u) {
    union { unsigned i; float f; } v; v.i = ((unsigned)u) << 16; return v.f;
}
static __device__ __forceinline__ u16 f2bf(float f) {         // RNE
    union { float f; unsigned i; } v; v.f = f;
    unsigned u = v.i;
    return (u16)((u + 0x7FFFu + ((u >> 16) & 1u)) >> 16);
}
// load 8 consecutive elements as a bf16 frag from fp32 OR bf16 storage
static __device__ __forceinline__ v8bf load8(const void* base, size_t off, bool f32) {
    union { u16 s[8]; v8bf v; } U;
    if (f32) {
        const float* p = (const float*)base + off;
        float4 a = *(const float4*)p;
        float4 b = *(const float4*)(p + 4);
        U.s[0] = f2bf(a.x); U.s[1] = f2bf(a.y); U.s[2] = f2bf(a.z); U.s[3] = f2bf(a.w);
        U.s[4] = f2bf(b.x); U.s[5] = f2bf(b.y); U.s[6] = f2bf(b.z); U.s[7] = f2bf(b.w);
    } else {
        U.v = *(const v8bf*)((const u16*)base + off);
    }
    return U.v;
}
static __device__ __forceinline__ float load1(const void* base, size_t off, bool f32) {
    return f32 ? ((const float*)base)[off] : bf2f(((const u16*)base)[off]);
}

// ---- dtype probe: bf16 vs fp32 device buffers ----
__global__ void probe_kernel(const unsigned* __restrict__ x, int* __restrict__ flag) {
    if (threadIdx.x == 0 && blockIdx.x == 0) {
        int b16like = 0;
        for (int i = 0; i < 128; i++) {
            unsigned lo = x[i] & 0xFFFFu;
            int e = (lo >> 7) & 0xFF;
            if (e >= 110 && e <= 140) b16like++;
        }
        *flag = (b16like >= 64) ? 0 : 1;   // 1 => fp32 inputs
    }
}

// =================== FAST PATH (uses workspace) ===================

// ---- K1: rpbT[h][col][row(pad 128)] fp32, 256KB, L2-hot in attn ----
__global__ __launch_bounds__(256) void rpbt_kernel(
    const void* __restrict__ rpb, const int* __restrict__ flag,
    float* __restrict__ rpbT)
{
    const bool f32 = (*flag != 0);
    const int h = blockIdx.x;
    for (int i = threadIdx.x; i < 16000; i += 256) {
        const int col = i >> 7, row = i & 127;
        float v = 0.f;
        if (row < 125) {
            const int p0 = row / 25, prem = row - p0 * 25, p1 = prem / 5, p2 = prem - p1 * 5;
            const int q0 = col / 25, qrem = col - q0 * 25, q1 = qrem / 5, q2 = qrem - q1 * 5;
            const int idx = (p0 - q0 + 4) * 81 + (p1 - q1 + 4) * 9 + (p2 - q2 + 4);
            v = load1(rpb, (size_t)idx * 4 + h, f32);
        }
        rpbT[(size_t)h * 16000 + i] = v;
    }
}

// ---- K2: QKV GEMM over the PADDED token grid (each batch padded 125->128 rows).
// q,k -> [s][b][h][n<125][32] bf16 ; v -> [s][b][h][d][128] bf16 (transposed, keys
// 125..127 are finite garbage, always multiplied by P=0 downstream).
// grid (4096, 6, 2) block 256 (4 waves, each 32x32 of a 64x64 tile)
__global__ __launch_bounds__(256) void qkv_kernel(
    const void* __restrict__ x, const void* __restrict__ y,
    const void* __restrict__ wqkvx, const void* __restrict__ bqkvx,
    const void* __restrict__ wqkvy, const void* __restrict__ bqkvy,
    const int* __restrict__ flag,
    u16* __restrict__ q, u16* __restrict__ k, u16* __restrict__ vT)
{
    const bool f32 = (*flag != 0);
    const int s = blockIdx.z;
    const void* A  = s ? y : x;
    const void* W  = s ? wqkvy : wqkvx;
    const void* bi = s ? bqkvy : bqkvx;
    const int bm = blockIdx.x, bn = blockIdx.y;
    const int tid = threadIdx.x, lane = tid & 63, wv = tid >> 6;
    const int wrow = (wv >> 1) * 32, wcol = (wv & 1) * 32;
    const int l15 = lane & 15, lg = lane >> 4;

    __shared__ u16 Wl[64][136];
    {
        const int r = tid >> 2, k0 = (tid & 3) * 32;
        #pragma unroll
        for (int i = 0; i < 4; i++)
            *(v8bf*)&Wl[r][k0 + i * 8] = load8(W, (size_t)(bn * 64 + r) * 128 + k0 + i * 8, f32);
    }
    __syncthreads();

    const int mbase = bm * 64 + wrow;                // padded-m space [0, 262144)
    v8bf af[2][4];
    #pragma unroll
    for (int mt = 0; mt < 2; mt++) {
        const int mr = mbase + mt * 16 + l15;
        const int b  = mr >> 7;
        int n = mr & 127; if (n > 124) n = 124;      // clamp pad rows
        const size_t arow = (size_t)(b * 125 + n) * 128;
        #pragma unroll
        for (int kk = 0; kk < 4; kk++)
            af[mt][kk] = load8(A, arow + kk * 32 + lg * 8, f32);
    }

    v8bf bfr[2][4];
    #pragma unroll
    for (int nt = 0; nt < 2; nt++)
        #pragma unroll
        for (int kk = 0; kk < 4; kk++)
            bfr[nt][kk] = *(const v8bf*)&Wl[wcol + nt * 16 + l15][kk * 32 + lg * 8];

    v4f acc[2][2];
    const v4f z4 = {0.f,0.f,0.f,0.f};
    #pragma unroll
    for (int mt = 0; mt < 2; mt++)
        #pragma unroll
        for (int nt = 0; nt < 2; nt++) acc[mt][nt] = z4;
    #pragma unroll
    for (int kk = 0; kk < 4; kk++)
        #pragma unroll
        for (int mt = 0; mt < 2; mt++)
            #pragma unroll
            for (int nt = 0; nt < 2; nt++)
                acc[mt][nt] = MFMA(af[mt][kk], bfr[nt][kk], acc[mt][nt]);

    #pragma unroll
    for (int mt = 0; mt < 2; mt++) {
        #pragma unroll
        for (int nt = 0; nt < 2; nt++) {
            const int cbase = bn * 64 + wcol + nt * 16;   // one (t,h,d16) group
            const int three = cbase >> 7;
            const int h     = (cbase >> 5) & 3;
            const int d     = (cbase & 31) + l15;
            const float bv  = load1(bi, cbase + l15, f32);
            if (three == 2) {
                // packed aligned 8B store: 4 consecutive keys (n0 % 4 == 0 always)
                const int m0 = mbase + mt * 16 + lg * 4;
                const int b  = m0 >> 7;
                const int n0 = m0 & 127;
                const size_t hb = (size_t)(s * 2048 + b) * 4 + h;
                u16x4 pk;
                #pragma unroll
                for (int ri = 0; ri < 4; ri++) pk[ri] = f2bf(acc[mt][nt][ri] + bv);
                *(u16x4*)&vT[hb * 4096 + (size_t)d * 128 + n0] = pk;
            } else {
                u16* dst = (three == 0) ? q : k;
                #pragma unroll
                for (int ri = 0; ri < 4; ri++) {
                    const int m = mbase + mt * 16 + lg * 4 + ri;
                    const int b = m >> 7;
                    const int n = m & 127;
                    if (n < 125) {
                        const size_t hb = (size_t)(s * 2048 + b) * 4 + h;
                        dst[hb * 4000 + n * 32 + d] = f2bf(acc[mt][nt][ri] + bv);
                    }
                }
            }
        }
    }
}

// ---- K3: window cross-attention. block = 256 thr (4 waves, one head each);
// XCD-swizzled so the 16 blocks sharing one mask slice land on one XCD L2.
__global__ __launch_bounds__(256) void attn_kernel(
    const u16* __restrict__ q, const u16* __restrict__ k, const u16* __restrict__ vT,
    const void* __restrict__ maskx, const void* __restrict__ masky,
    const float* __restrict__ rpbT, const int* __restrict__ flag,
    float* __restrict__ out)
{
    const bool f32 = (*flag != 0);
    const int bid = blockIdx.x;                    // 4096 = 8 xcd * 512
    const int rep = (bid >> 3) & 15;               // same-w blocks -> same XCD
    const int w   = ((bid >> 7) << 3) | (bid & 7);
    const int s = rep & 1, b = (rep >> 1) * 256 + w;
    const int tid = threadIdx.x;
    const int hv = tid >> 6;                       // wave = head
    const int lane = tid & 63, l15 = lane & 15, lg = lane >> 4;

    __shared__ u16 Pb[4][32][136];                 // per-wave P partition
    u16* P = &Pb[hv][0][0];

    const u16* qb = q  + ((size_t)(s * 2048 + b) * 4 + hv) * 4000;
    const u16* kb = k  + ((size_t)((1 - s) * 2048 + b) * 4 + hv) * 4000;
    const u16* vb = vT + ((size_t)((1 - s) * 2048 + b) * 4 + hv) * 4096;
    const void* msk = s ? masky : maskx;
    const size_t mbase = (size_t)w * 15625;
    const float* rT = rpbT + (size_t)hv * 16000;

    v8bf kf[8];                                    // resident K frags
    #pragma unroll
    for (int jt = 0; jt < 8; jt++) {
        int r = jt * 16 + l15; if (r > 124) r = 124;
        kf[jt] = *(const v8bf*)(kb + r * 32 + lg * 8);
    }

    int colc[8];
    #pragma unroll
    for (int jt = 0; jt < 8; jt++) {
        int c = jt * 16 + l15; if (c > 124) c = 124;
        colc[jt] = c;
    }
    const float scale = 0.17677669529663689f;      // 32^-0.5
    const v4f z4 = {0.f,0.f,0.f,0.f};

    for (int ch = 0; ch < 4; ch++) {
        v8bf qf[2];
        #pragma unroll
        for (int mt = 0; mt < 2; mt++) {
            int r = ch * 32 + mt * 16 + l15; if (r > 124) r = 124;
            qf[mt] = *(const v8bf*)(qb + r * 32 + lg * 8);
        }
        v4f acc[2][8];
        #pragma unroll
        for (int mt = 0; mt < 2; mt++)
            #pragma unroll
            for (int jt = 0; jt < 8; jt++) acc[mt][jt] = z4;
        #pragma unroll
        for (int jt = 0; jt < 8; jt++)
            #pragma unroll
            for (int mt = 0; mt < 2; mt++)
                acc[mt][jt] = MFMA(qf[mt], kf[jt], acc[mt][jt]);

        float rinv[2][4];
        #pragma unroll
        for (int mt = 0; mt < 2; mt++) {
            const int rowb = ch * 32 + mt * 16 + lg * 4;
            const bool tail = (ch == 3) && (mt == 1);        // only place rows >=125 occur

            float4 c4[8];                    // rpb bias, unconditional float4 gathers
            #pragma unroll
            for (int jt = 0; jt < 8; jt++)
                c4[jt] = *(const float4*)(rT + colc[jt] * 128 + rowb);

            float mreg[4][8];                // mask prefetch: 32 unconditional loads
            #pragma unroll
            for (int ri = 0; ri < 4; ri++) {
                int rc = rowb + ri; if (rc > 124) rc = 124;
                const size_t moff = mbase + (size_t)rc * 125;
                #pragma unroll
                for (int jt = 0; jt < 8; jt++)
                    mreg[ri][jt] = load1(msk, moff + colc[jt], f32);
            }

            #pragma unroll
            for (int ri = 0; ri < 4; ri++) {
                const int row = rowb + ri;
                const bool rv = !tail || (row < 125);
                #pragma unroll
                for (int jt = 0; jt < 8; jt++) {
                    const float t = fmaf(acc[mt][jt][ri], scale,
                                         (&c4[jt].x)[ri] + mreg[ri][jt]);
                    // jt<7: col always valid; jt=7: lanes l15>12 invalid
                    const bool cv = (jt < 7) | (l15 < 13);
                    acc[mt][jt][ri] = (rv & cv) ? t : -1e30f;
                }
                float mx = acc[mt][0][ri];
                #pragma unroll
                for (int jt = 1; jt < 8; jt++) mx = fmaxf(mx, acc[mt][jt][ri]);
                mx = fmaxf(mx, __shfl_xor(mx, 1));
                mx = fmaxf(mx, __shfl_xor(mx, 2));
                mx = fmaxf(mx, __shfl_xor(mx, 4));
                mx = fmaxf(mx, __shfl_xor(mx, 8));
                float sum = 0.f;
                #pragma unroll
                for (int jt = 0; jt < 8; jt++) {
                    const float pv = __expf(acc[mt][jt][ri] - mx);
                    acc[mt][jt][ri] = pv; sum += pv;
                }
                sum += __shfl_xor(sum, 1);
                sum += __shfl_xor(sum, 2);
                sum += __shfl_xor(sum, 4);
                sum += __shfl_xor(sum, 8);
                rinv[mt][ri] = 1.0f / sum;   // folded into O
            }
        }

        // P (D-layout) -> LDS (A-layout); wave-local, no barrier
        #pragma unroll
        for (int mt = 0; mt < 2; mt++)
            #pragma unroll
            for (int jt = 0; jt < 8; jt++)
                #pragma unroll
                for (int ri = 0; ri < 4; ri++)
                    P[(mt * 16 + lg * 4 + ri) * 136 + jt * 16 + l15] = f2bf(acc[mt][jt][ri]);

        // V frags per chunk (L2-hot after chunk 0; keeps softmax-phase VGPR lower)
        v8bf vf[2][4];
        #pragma unroll
        for (int n2 = 0; n2 < 2; n2++)
            #pragma unroll
            for (int kk = 0; kk < 4; kk++)
                vf[n2][kk] = *(const v8bf*)(vb + (n2 * 16 + l15) * 128 + kk * 32 + lg * 8);

        v4f o[2][2];
        #pragma unroll
        for (int mt = 0; mt < 2; mt++)
            #pragma unroll
            for (int n2 = 0; n2 < 2; n2++) o[mt][n2] = z4;
        #pragma unroll
        for (int mt = 0; mt < 2; mt++) {
            v8bf pa[4];
            #pragma unroll
            for (int kk = 0; kk < 4; kk++)
                pa[kk] = *(const v8bf*)&P[(mt * 16 + l15) * 136 + kk * 32 + lg * 8];
            #pragma unroll
            for (int n2 = 0; n2 < 2; n2++)
                #pragma unroll
                for (int kk = 0; kk < 4; kk++)
                    o[mt][n2] = MFMA(pa[kk], vf[n2][kk], o[mt][n2]);
        }

        #pragma unroll
        for (int mt = 0; mt < 2; mt++)
            #pragma unroll
            for (int n2 = 0; n2 < 2; n2++)
                #pragma unroll
                for (int ri = 0; ri < 4; ri++) {
                    const int row = ch * 32 + mt * 16 + lg * 4 + ri;
                    if (row < 125)
                        out[((size_t)s * 256000 + (size_t)b * 125 + row) * 128
                            + hv * 32 + n2 * 16 + l15] = o[mt][n2][ri] * rinv[mt][ri];
                }
    }
}

// =================== SLOW PATH (round-3 validated fallback) ===================

__global__ __launch_bounds__(64) void fused_attn(
    const void* __restrict__ x, const void* __restrict__ y,
    const void* __restrict__ maskx, const void* __restrict__ masky,
    const void* __restrict__ wqkvx, const void* __restrict__ bqkvx,
    const void* __restrict__ wqkvy, const void* __restrict__ bqkvy,
    const void* __restrict__ rpb, const int* __restrict__ flag,
    float* __restrict__ out)
{
    const bool f32 = (*flag != 0);
    const int b = blockIdx.x >> 1;
    const int s = blockIdx.x & 1;
    const int h = blockIdx.y;
    const int lane = threadIdx.x;
    const int l15 = lane & 15, lg = lane >> 4;

    __shared__ u16 QL[125][40];
    __shared__ u16 KL[125][40];
    __shared__ u16 VT[32][136];
    __shared__ u16 P[32][136];

    const void* inS = s ? y : x;
    const void* inO = s ? x : y;
    const void* wS  = s ? wqkvy : wqkvx;
    const void* wO  = s ? wqkvx : wqkvy;
    const void* bS  = s ? bqkvy : bqkvx;
    const void* bO  = s ? bqkvx : bqkvy;
    const void* msk = s ? masky : maskx;

    const size_t inb = (size_t)b * (125 * 128);

    #pragma unroll
    for (int t = 0; t < 3; t++) {
        const void* src = t ? inO : inS;
        const void* wp  = t ? wO  : wS;
        const void* bp  = t ? bO  : bS;
        const int wrow = t * 128 + h * 32;

        v8bf bfr[2][4];
        float bv[2];
        #pragma unroll
        for (int nt = 0; nt < 2; nt++) {
            bv[nt] = load1(bp, wrow + nt * 16 + l15, f32);
            #pragma unroll
            for (int kk = 0; kk < 4; kk++)
                bfr[nt][kk] = load8(wp, (size_t)(wrow + nt * 16 + l15) * 128 + kk * 32 + lg * 8, f32);
        }
        #pragma unroll
        for (int mt = 0; mt < 8; mt++) {
            int ar = mt * 16 + l15; if (ar > 124) ar = 124;
            v8bf af[4];
            #pragma unroll
            for (int kk = 0; kk < 4; kk++)
                af[kk] = load8(src, inb + (size_t)ar * 128 + kk * 32 + lg * 8, f32);
            v4f a0 = {0.f,0.f,0.f,0.f}, a1 = {0.f,0.f,0.f,0.f};
            #pragma unroll
            for (int kk = 0; kk < 4; kk++) {
                a0 = MFMA(af[kk], bfr[0][kk], a0);
                a1 = MFMA(af[kk], bfr[1][kk], a1);
            }
            #pragma unroll
            for (int nt = 0; nt < 2; nt++) {
                const v4f acc = nt ? a1 : a0;
                const int col = nt * 16 + l15;
                #pragma unroll
                for (int ri = 0; ri < 4; ri++) {
                    const int wr = mt * 16 + lg * 4 + ri;
                    if (wr < 125) {
                        const u16 val = f2bf(acc[ri] + bv[nt]);
                        if (t == 0)      QL[wr][col] = val;
                        else if (t == 1) KL[wr][col] = val;
                        else             VT[col][wr] = val;
                    }
                }
            }
        }
    }
    for (int z = lane; z < 96; z += 64) VT[z & 31][125 + (z >> 5)] = 0;
    __syncthreads();

    v8bf kf[8];
    #pragma unroll
    for (int jt = 0; jt < 8; jt++) {
        int r = jt * 16 + l15; if (r > 124) r = 124;
        kf[jt] = *(const v8bf*)&KL[r][lg * 8];
    }
    v8bf vf[2][4];
    #pragma unroll
    for (int n2 = 0; n2 < 2; n2++)
        #pragma unroll
        for (int kk = 0; kk < 4; kk++)
            vf[n2][kk] = *(const v8bf*)&VT[n2 * 16 + l15][kk * 32 + lg * 8];

    int cb[8];
    #pragma unroll
    for (int jt = 0; jt < 8; jt++) {
        int col = jt * 16 + l15; if (col > 124) col = 124;
        const int q0 = col / 25, rem = col - q0 * 25, q1 = rem / 5, q2 = rem - q1 * 5;
        cb[jt] = 364 - (q0 * 81 + q1 * 9 + q2);
    }
    const size_t mbase = (size_t)(b & 255) * 15625;
    const float scale = 0.17677669529663689f;
    const v4f z4 = {0.f,0.f,0.f,0.f};

    for (int ch = 0; ch < 4; ch++) {
        v8bf qf[2];
        #pragma unroll
        for (int mt = 0; mt < 2; mt++) {
            int r = ch * 32 + mt * 16 + l15; if (r > 124) r = 124;
            qf[mt] = *(const v8bf*)&QL[r][lg * 8];
        }
        v4f acc[2][8];
        #pragma unroll
        for (int mt = 0; mt < 2; mt++)
            #pragma unroll
            for (int jt = 0; jt < 8; jt++) acc[mt][jt] = z4;
        #pragma unroll
        for (int jt = 0; jt < 8; jt++)
            #pragma unroll
            for (int mt = 0; mt < 2; mt++)
                acc[mt][jt] = MFMA(qf[mt], kf[jt], acc[mt][jt]);

        float rinv[2][4];
        #pragma unroll
        for (int mt = 0; mt < 2; mt++) {
            #pragma unroll
            for (int ri = 0; ri < 4; ri++) {
                const int row = ch * 32 + mt * 16 + lg * 4 + ri;
                const bool rv = row < 125;
                int prow = 0; size_t moff = 0;
                if (rv) {
                    const int p0 = row / 25, rem = row - p0 * 25, p1 = rem / 5, p2 = rem - p1 * 5;
                    prow = p0 * 81 + p1 * 9 + p2;
                    moff = mbase + (size_t)row * 125;
                }
                #pragma unroll
                for (int jt = 0; jt < 8; jt++) {
                    const int col = jt * 16 + l15;
                    float vv = -1e30f;
                    if (rv && col < 125)
                        vv = acc[mt][jt][ri] * scale
                           + load1(rpb, (size_t)(prow + cb[jt]) * 4 + h, f32)
                           + load1(msk, moff + col, f32);
                    acc[mt][jt][ri] = vv;
                }
                float mx = acc[mt][0][ri];
                #pragma unroll
                for (int jt = 1; jt < 8; jt++) mx = fmaxf(mx, acc[mt][jt][ri]);
                mx = fmaxf(mx, __shfl_xor(mx, 1));
                mx = fmaxf(mx, __shfl_xor(mx, 2));
                mx = fmaxf(mx, __shfl_xor(mx, 4));
                mx = fmaxf(mx, __shfl_xor(mx, 8));
                float sum = 0.f;
                #pragma unroll
                for (int jt = 0; jt < 8; jt++) {
                    const float pv = __expf(acc[mt][jt][ri] - mx);
                    acc[mt][jt][ri] = pv; sum += pv;
                }
                sum += __shfl_xor(sum, 1);
                sum += __shfl_xor(sum, 2);
                sum += __shfl_xor(sum, 4);
                sum += __shfl_xor(sum, 8);
                rinv[mt][ri] = 1.0f / sum;
            }
        }

        __syncthreads();
        #pragma unroll
        for (int mt = 0; mt < 2; mt++)
            #pragma unroll
            for (int jt = 0; jt < 8; jt++)
                #pragma unroll
                for (int ri = 0; ri < 4; ri++)
                    P[mt * 16 + lg * 4 + ri][jt * 16 + l15] = f2bf(acc[mt][jt][ri]);
        __syncthreads();

        v4f o[2][2];
        #pragma unroll
        for (int mt = 0; mt < 2; mt++)
            #pragma unroll
            for (int n2 = 0; n2 < 2; n2++) o[mt][n2] = z4;
        #pragma unroll
        for (int mt = 0; mt < 2; mt++) {
            v8bf pa[4];
            #pragma unroll
            for (int kk = 0; kk < 4; kk++)
                pa[kk] = *(const v8bf*)&P[mt * 16 + l15][kk * 32 + lg * 8];
            #pragma unroll
            for (int n2 = 0; n2 < 2; n2++)
                #pragma unroll
                for (int kk = 0; kk < 4; kk++)
                    o[mt][n2] = MFMA(pa[kk], vf[n2][kk], o[mt][n2]);
        }

        #pragma unroll
        for (int mt = 0; mt < 2; mt++)
            #pragma unroll
            for (int n2 = 0; n2 < 2; n2++)
                #pragma unroll
                for (int ri = 0; ri < 4; ri++) {
                    const int row = ch * 32 + mt * 16 + lg * 4 + ri;
                    if (row < 125)
                        out[((size_t)s * 256000 + (size_t)b * 125 + row) * 128
                            + h * 32 + n2 * 16 + l15] = o[mt][n2][ri] * rinv[mt][ri];
                }
    }
}

// ---- output projection, in place on fp32 d_out (shared by both paths) ----
__global__ __launch_bounds__(256) void proj_kernel(
    const void* __restrict__ wpx, const void* __restrict__ bpx,
    const void* __restrict__ wpy, const void* __restrict__ bpy,
    const int* __restrict__ flag, float* io)
{
    const bool f32 = (*flag != 0);
    const int s  = blockIdx.y;
    const int bm = blockIdx.x;
    const void* W    = s ? wpy : wpx;
    const void* bias = s ? bpy : bpx;
    float* A = io + (size_t)s * 32768000;
    const int tid = threadIdx.x, lane = tid & 63, wv = tid >> 6;
    const int l15 = lane & 15, lg = lane >> 4;

    __shared__ u16 Wl[128][136];
    for (int i = tid * 8; i < 16384; i += 2048)
        *(v8bf*)&Wl[i >> 7][i & 127] = load8(W, i, f32);
    __syncthreads();

    const int mbase = bm * 64 + wv * 16;
    v4f acc[8];
    const v4f z4 = {0.f,0.f,0.f,0.f};
    #pragma unroll
    for (int nt = 0; nt < 8; nt++) acc[nt] = z4;

    const float* Ar = A + (size_t)(mbase + l15) * 128;
    v8bf afr[4];
    #pragma unroll
    for (int kk = 0; kk < 4; kk++) {
        union { u16 sI[8]; v8bf v; } U;
        float4 fa = *(const float4*)(Ar + kk * 32 + lg * 8);
        float4 fb = *(const float4*)(Ar + kk * 32 + lg * 8 + 4);
        U.sI[0] = f2bf(fa.x); U.sI[1] = f2bf(fa.y); U.sI[2] = f2bf(fa.z); U.sI[3] = f2bf(fa.w);
        U.sI[4] = f2bf(fb.x); U.sI[5] = f2bf(fb.y); U.sI[6] = f2bf(fb.z); U.sI[7] = f2bf(fb.w);
        afr[kk] = U.v;
    }
    #pragma unroll
    for (int kk = 0; kk < 4; kk++)
        #pragma unroll
        for (int nt = 0; nt < 8; nt++)
            acc[nt] = MFMA(afr[kk], *(const v8bf*)&Wl[nt * 16 + l15][kk * 32 + lg * 8], acc[nt]);

    #pragma unroll
    for (int nt = 0; nt < 8; nt++) {
        const int c = nt * 16 + l15;
        const float bv = load1(bias, c, f32);
        #pragma unroll
        for (int ri = 0; ri < 4; ri++)
            A[(size_t)(mbase + lg * 4 + ri) * 128 + c] = acc[nt][ri] + bv;
    }
}

extern "C" void kernel_launch(void* const* d_in, const int* in_sizes, int n_in,
                              void* d_out, int out_size, void* d_ws, size_t ws_size,
                              hipStream_t stream) {
    const void* x     = d_in[0];
    const void* y     = d_in[1];
    const void* maskx = d_in[2];
    const void* masky = d_in[3];
    const void* wqx   = d_in[4];
    const void* bqx   = d_in[5];
    const void* wqy   = d_in[6];
    const void* bqy   = d_in[7];
    const void* wpx   = d_in[8];
    const void* bpx   = d_in[9];
    const void* wpy   = d_in[10];
    const void* bpy   = d_in[11];
    const void* rpb   = d_in[12];

    // fast-path workspace layout (bytes)
    const size_t OFF_RPBT = 0;                       // 64000 f32   = 256,000 B
    const size_t OFF_Q    = 256000;                  // 65.536M bf16 = 131,072,000 B
    const size_t OFF_K    = OFF_Q + 131072000;
    const size_t OFF_VT   = OFF_K + 131072000;       // 67.109M bf16 = 134,217,728 B
    const size_t OFF_FLAG = OFF_VT + 134217728;
    const size_t NEED     = OFF_FLAG + 4;            // 396,617,732 B

    if (ws_size >= NEED) {
        float* rpbT = (float*)((char*)d_ws + OFF_RPBT);
        u16*   q    = (u16*)((char*)d_ws + OFF_Q);
        u16*   k    = (u16*)((char*)d_ws + OFF_K);
        u16*   vT   = (u16*)((char*)d_ws + OFF_VT);
        int*   flag = (int*)((char*)d_ws + OFF_FLAG);

        probe_kernel<<<1, 64, 0, stream>>>((const unsigned*)x, flag);
        rpbt_kernel<<<4, 256, 0, stream>>>(rpb, flag, rpbT);
        qkv_kernel<<<dim3(4096, 6, 2), 256, 0, stream>>>(x, y, wqx, bqx, wqy, bqy,
                                                         flag, q, k, vT);
        attn_kernel<<<4096, 256, 0, stream>>>(q, k, vT, maskx, masky, rpbT, flag,
                                              (float*)d_out);
        proj_kernel<<<dim3(4000, 2), 256, 0, stream>>>(wpx, bpx, wpy, bpy,
                                                       flag, (float*)d_out);
    } else {
        int* flag = (int*)d_ws;
        probe_kernel<<<1, 64, 0, stream>>>((const unsigned*)x, flag);
        fused_attn<<<dim3(4096, 4), 64, 0, stream>>>(x, y, maskx, masky,
                                                     wqx, bqx, wqy, bqy,
                                                     rpb, flag, (float*)d_out);
        proj_kernel<<<dim3(4000, 2), 256, 0, stream>>>(wpx, bpx, wpy, bpy,
                                                       flag, (float*)d_out);
    }
}

// Round 6
// 882.307 us; speedup vs baseline: 3.4006x; 1.3612x over previous
//
#include <hip/hip_runtime.h>
#include <stdint.h>

typedef unsigned short u16;                                   // raw bf16 bits
typedef __bf16 v8bf __attribute__((ext_vector_type(8)));      // MFMA A/B frag
typedef float  v4f  __attribute__((ext_vector_type(4)));      // MFMA C/D frag
typedef u16    u16x4 __attribute__((ext_vector_type(4)));

#define MFMA(a,b,c) __builtin_amdgcn_mfma_f32_16x16x32_bf16((a),(b),(c),0,0,0)

static __device__ __forceinline__ float bf2f(u16 u) {
    union { unsigned i; float f; } v; v.i = ((unsigned)u) << 16; return v.f;
}
static __device__ __forceinline__ u16 f2bf(float f) {         // RNE
    union { float f; unsigned i; } v; v.f = f;
    unsigned u = v.i;
    return (u16)((u + 0x7FFFu + ((u >> 16) & 1u)) >> 16);
}
// load 8 consecutive elements as a bf16 frag from fp32 OR bf16 storage
static __device__ __forceinline__ v8bf load8(const void* base, size_t off, bool f32) {
    union { u16 s[8]; v8bf v; } U;
    if (f32) {
        const float* p = (const float*)base + off;
        float4 a = *(const float4*)p;
        float4 b = *(const float4*)(p + 4);
        U.s[0] = f2bf(a.x); U.s[1] = f2bf(a.y); U.s[2] = f2bf(a.z); U.s[3] = f2bf(a.w);
        U.s[4] = f2bf(b.x); U.s[5] = f2bf(b.y); U.s[6] = f2bf(b.z); U.s[7] = f2bf(b.w);
    } else {
        U.v = *(const v8bf*)((const u16*)base + off);
    }
    return U.v;
}
static __device__ __forceinline__ float load1(const void* base, size_t off, bool f32) {
    return f32 ? ((const float*)base)[off] : bf2f(((const u16*)base)[off]);
}

// ---- dtype probe: bf16 vs fp32 device buffers ----
__global__ void probe_kernel(const unsigned* __restrict__ x, int* __restrict__ flag) {
    if (threadIdx.x == 0 && blockIdx.x == 0) {
        int b16like = 0;
        for (int i = 0; i < 128; i++) {
            unsigned lo = x[i] & 0xFFFFu;
            int e = (lo >> 7) & 0xFF;
            if (e >= 110 && e <= 140) b16like++;
        }
        *flag = (b16like >= 64) ? 0 : 1;   // 1 => fp32 inputs
    }
}

// =================== FAST PATH (uses workspace) ===================

// ---- K0b: convert qkv weights+biases to bf16 into region0 (phase-1 use).
// wb: [2][384][128] bf16 (196608 elems... bytes), bb: [2][384] bf16 ----
__global__ __launch_bounds__(256) void wconv_kernel(
    const void* __restrict__ wqkvx, const void* __restrict__ bqkvx,
    const void* __restrict__ wqkvy, const void* __restrict__ bqkvy,
    const int* __restrict__ flag, u16* __restrict__ wb, u16* __restrict__ bb)
{
    const bool f32 = (*flag != 0);
    const int s = blockIdx.y;
    const void* W = s ? wqkvy : wqkvx;
    const void* B = s ? bqkvy : bqkvx;
    const int i = blockIdx.x * 256 + threadIdx.x;      // grid.x = 192 -> 49152
    wb[(size_t)s * 49152 + i] = f2bf(load1(W, i, f32));
    if (i < 384) bb[s * 384 + i] = f2bf(load1(B, i, f32));
}

// ---- K1: rpbT[h][col][row(pad 128)] fp32, 256KB, L2-hot in attn.
// Runs AFTER qkv (overwrites the wb/bb region). ----
__global__ __launch_bounds__(256) void rpbt_kernel(
    const void* __restrict__ rpb, const int* __restrict__ flag,
    float* __restrict__ rpbT)
{
    const bool f32 = (*flag != 0);
    const int h = blockIdx.x;
    for (int i = threadIdx.x; i < 16000; i += 256) {
        const int col = i >> 7, row = i & 127;
        float v = 0.f;
        if (row < 125) {
            const int p0 = row / 25, prem = row - p0 * 25, p1 = prem / 5, p2 = prem - p1 * 5;
            const int q0 = col / 25, qrem = col - q0 * 25, q1 = qrem / 5, q2 = qrem - q1 * 5;
            const int idx = (p0 - q0 + 4) * 81 + (p1 - q1 + 4) * 9 + (p2 - q2 + 4);
            v = load1(rpb, (size_t)idx * 4 + h, f32);
        }
        rpbT[(size_t)h * 16000 + i] = v;
    }
}

// ---- K2: QKV GEMM, A read ONCE per block. Each block: 128 padded rows x all
// 384 cols; 4 waves x 32 rows. B-frags straight from L2-resident bf16 weights
// (no LDS, no barriers). q,k -> [s][b][h][n<125][32]; v -> [s][b][h][d][128].
// grid (2048, 2) block 256
__global__ __launch_bounds__(256) void qkv_kernel(
    const void* __restrict__ x, const void* __restrict__ y,
    const u16* __restrict__ wb, const u16* __restrict__ bb,
    const int* __restrict__ flag,
    u16* __restrict__ q, u16* __restrict__ k, u16* __restrict__ vT)
{
    const bool f32 = (*flag != 0);
    const int s = blockIdx.y;
    const void* A = s ? y : x;
    const u16* W  = wb + (size_t)s * 49152;
    const u16* Bb = bb + s * 384;
    const int tid = threadIdx.x, lane = tid & 63, wv = tid >> 6;
    const int l15 = lane & 15, lg = lane >> 4;

    const int mbase = blockIdx.x * 128 + wv * 32;    // padded-m space [0, 262144)

    // A frags for this wave's 32 rows, converted once
    v8bf af[2][4];
    #pragma unroll
    for (int mt = 0; mt < 2; mt++) {
        const int mr = mbase + mt * 16 + l15;
        const int b  = mr >> 7;
        int n = mr & 127; if (n > 124) n = 124;      // clamp pad rows
        const size_t arow = (size_t)(b * 125 + n) * 128;
        #pragma unroll
        for (int kk = 0; kk < 4; kk++)
            af[mt][kk] = load8(A, arow + kk * 32 + lg * 8, f32);
    }

    const v4f z4 = {0.f,0.f,0.f,0.f};
    #pragma unroll
    for (int nt = 0; nt < 24; nt++) {
        const int col0 = nt * 16;
        v8bf bfr[4];
        #pragma unroll
        for (int kk = 0; kk < 4; kk++)
            bfr[kk] = *(const v8bf*)(W + (size_t)(col0 + l15) * 128 + kk * 32 + lg * 8);
        const float bv = bf2f(Bb[col0 + l15]);

        v4f a0 = z4, a1 = z4;
        #pragma unroll
        for (int kk = 0; kk < 4; kk++) {
            a0 = MFMA(af[0][kk], bfr[kk], a0);
            a1 = MFMA(af[1][kk], bfr[kk], a1);
        }

        const int three = col0 >> 7;                 // 0=q 1=k 2=v
        const int h     = (col0 >> 5) & 3;
        const int d     = (col0 & 31) + l15;
        #pragma unroll
        for (int mt = 0; mt < 2; mt++) {
            const v4f acc = mt ? a1 : a0;
            const int m0 = mbase + mt * 16 + lg * 4;
            const int b  = m0 >> 7;
            const int n0 = m0 & 127;                 // multiple of 4
            const size_t hb = (size_t)(s * 2048 + b) * 4 + h;
            if (three == 2) {
                u16x4 pk;
                #pragma unroll
                for (int ri = 0; ri < 4; ri++) pk[ri] = f2bf(acc[ri] + bv);
                *(u16x4*)&vT[hb * 4096 + (size_t)d * 128 + n0] = pk;
            } else {
                u16* dst = (three == 0) ? q : k;
                #pragma unroll
                for (int ri = 0; ri < 4; ri++) {
                    const int n = n0 + ri;
                    if (n < 125)
                        dst[hb * 4000 + n * 32 + d] = f2bf(acc[ri] + bv);
                }
            }
        }
    }
}

// ---- K3: window cross-attention. block = 256 thr (4 waves, one head each);
// XCD-swizzled so the 16 blocks sharing one mask slice land on one XCD L2.
__global__ __launch_bounds__(256) void attn_kernel(
    const u16* __restrict__ q, const u16* __restrict__ k, const u16* __restrict__ vT,
    const void* __restrict__ maskx, const void* __restrict__ masky,
    const float* __restrict__ rpbT, const int* __restrict__ flag,
    float* __restrict__ out)
{
    const bool f32 = (*flag != 0);
    const int bid = blockIdx.x;                    // 4096 = 8 xcd * 512
    const int rep = (bid >> 3) & 15;               // same-w blocks -> same XCD
    const int w   = ((bid >> 7) << 3) | (bid & 7);
    const int s = rep & 1, b = (rep >> 1) * 256 + w;
    const int tid = threadIdx.x;
    const int hv = tid >> 6;                       // wave = head
    const int lane = tid & 63, l15 = lane & 15, lg = lane >> 4;

    __shared__ u16 Pb[4][32][136];                 // per-wave P partition
    u16* P = &Pb[hv][0][0];

    const u16* qb = q  + ((size_t)(s * 2048 + b) * 4 + hv) * 4000;
    const u16* kb = k  + ((size_t)((1 - s) * 2048 + b) * 4 + hv) * 4000;
    const u16* vb = vT + ((size_t)((1 - s) * 2048 + b) * 4 + hv) * 4096;
    const void* msk = s ? masky : maskx;
    const size_t mbase = (size_t)w * 15625;
    const float* rT = rpbT + (size_t)hv * 16000;

    v8bf kf[8];                                    // resident K frags
    #pragma unroll
    for (int jt = 0; jt < 8; jt++) {
        int r = jt * 16 + l15; if (r > 124) r = 124;
        kf[jt] = *(const v8bf*)(kb + r * 32 + lg * 8);
    }

    int colc[8];
    #pragma unroll
    for (int jt = 0; jt < 8; jt++) {
        int c = jt * 16 + l15; if (c > 124) c = 124;
        colc[jt] = c;
    }
    const float scale = 0.17677669529663689f;      // 32^-0.5
    const v4f z4 = {0.f,0.f,0.f,0.f};

    for (int ch = 0; ch < 4; ch++) {
        v8bf qf[2];
        #pragma unroll
        for (int mt = 0; mt < 2; mt++) {
            int r = ch * 32 + mt * 16 + l15; if (r > 124) r = 124;
            qf[mt] = *(const v8bf*)(qb + r * 32 + lg * 8);
        }
        v4f acc[2][8];
        #pragma unroll
        for (int mt = 0; mt < 2; mt++)
            #pragma unroll
            for (int jt = 0; jt < 8; jt++) acc[mt][jt] = z4;
        #pragma unroll
        for (int jt = 0; jt < 8; jt++)
            #pragma unroll
            for (int mt = 0; mt < 2; mt++)
                acc[mt][jt] = MFMA(qf[mt], kf[jt], acc[mt][jt]);

        float rinv[2][4];
        #pragma unroll
        for (int mt = 0; mt < 2; mt++) {
            const int rowb = ch * 32 + mt * 16 + lg * 4;
            const bool tail = (ch == 3) && (mt == 1);        // only rows >=125 here

            float4 c4[8];                    // rpb bias, unconditional float4 gathers
            #pragma unroll
            for (int jt = 0; jt < 8; jt++)
                c4[jt] = *(const float4*)(rT + colc[jt] * 128 + rowb);

            float mreg[4][8];                // mask prefetch: 32 unconditional loads
            #pragma unroll
            for (int ri = 0; ri < 4; ri++) {
                int rc = rowb + ri; if (rc > 124) rc = 124;
                const size_t moff = mbase + (size_t)rc * 125;
                #pragma unroll
                for (int jt = 0; jt < 8; jt++)
                    mreg[ri][jt] = load1(msk, moff + colc[jt], f32);
            }

            #pragma unroll
            for (int ri = 0; ri < 4; ri++) {
                const int row = rowb + ri;
                const bool rv = !tail || (row < 125);
                #pragma unroll
                for (int jt = 0; jt < 8; jt++) {
                    const float t = fmaf(acc[mt][jt][ri], scale,
                                         (&c4[jt].x)[ri] + mreg[ri][jt]);
                    // jt<7: col always valid; jt=7: lanes l15>12 invalid
                    const bool cv = (jt < 7) | (l15 < 13);
                    acc[mt][jt][ri] = (rv & cv) ? t : -1e30f;
                }
                float mx = acc[mt][0][ri];
                #pragma unroll
                for (int jt = 1; jt < 8; jt++) mx = fmaxf(mx, acc[mt][jt][ri]);
                mx = fmaxf(mx, __shfl_xor(mx, 1));
                mx = fmaxf(mx, __shfl_xor(mx, 2));
                mx = fmaxf(mx, __shfl_xor(mx, 4));
                mx = fmaxf(mx, __shfl_xor(mx, 8));
                float sum = 0.f;
                #pragma unroll
                for (int jt = 0; jt < 8; jt++) {
                    const float pv = __expf(acc[mt][jt][ri] - mx);
                    acc[mt][jt][ri] = pv; sum += pv;
                }
                sum += __shfl_xor(sum, 1);
                sum += __shfl_xor(sum, 2);
                sum += __shfl_xor(sum, 4);
                sum += __shfl_xor(sum, 8);
                rinv[mt][ri] = 1.0f / sum;   // folded into O
            }
        }

        // P (D-layout) -> LDS (A-layout); wave-local, no barrier
        #pragma unroll
        for (int mt = 0; mt < 2; mt++)
            #pragma unroll
            for (int jt = 0; jt < 8; jt++)
                #pragma unroll
                for (int ri = 0; ri < 4; ri++)
                    P[(mt * 16 + lg * 4 + ri) * 136 + jt * 16 + l15] = f2bf(acc[mt][jt][ri]);

        // V frags per chunk (L2-hot after chunk 0)
        v8bf vf[2][4];
        #pragma unroll
        for (int n2 = 0; n2 < 2; n2++)
            #pragma unroll
            for (int kk = 0; kk < 4; kk++)
                vf[n2][kk] = *(const v8bf*)(vb + (n2 * 16 + l15) * 128 + kk * 32 + lg * 8);

        v4f o[2][2];
        #pragma unroll
        for (int mt = 0; mt < 2; mt++)
            #pragma unroll
            for (int n2 = 0; n2 < 2; n2++) o[mt][n2] = z4;
        #pragma unroll
        for (int mt = 0; mt < 2; mt++) {
            v8bf pa[4];
            #pragma unroll
            for (int kk = 0; kk < 4; kk++)
                pa[kk] = *(const v8bf*)&P[(mt * 16 + l15) * 136 + kk * 32 + lg * 8];
            #pragma unroll
            for (int n2 = 0; n2 < 2; n2++)
                #pragma unroll
                for (int kk = 0; kk < 4; kk++)
                    o[mt][n2] = MFMA(pa[kk], vf[n2][kk], o[mt][n2]);
        }

        #pragma unroll
        for (int mt = 0; mt < 2; mt++)
            #pragma unroll
            for (int n2 = 0; n2 < 2; n2++)
                #pragma unroll
                for (int ri = 0; ri < 4; ri++) {
                    const int row = ch * 32 + mt * 16 + lg * 4 + ri;
                    if (row < 125)
                        out[((size_t)s * 256000 + (size_t)b * 125 + row) * 128
                            + hv * 32 + n2 * 16 + l15] = o[mt][n2][ri] * rinv[mt][ri];
                }
    }
}

// =================== SLOW PATH (round-3 validated fallback) ===================

__global__ __launch_bounds__(64) void fused_attn(
    const void* __restrict__ x, const void* __restrict__ y,
    const void* __restrict__ maskx, const void* __restrict__ masky,
    const void* __restrict__ wqkvx, const void* __restrict__ bqkvx,
    const void* __restrict__ wqkvy, const void* __restrict__ bqkvy,
    const void* __restrict__ rpb, const int* __restrict__ flag,
    float* __restrict__ out)
{
    const bool f32 = (*flag != 0);
    const int b = blockIdx.x >> 1;
    const int s = blockIdx.x & 1;
    const int h = blockIdx.y;
    const int lane = threadIdx.x;
    const int l15 = lane & 15, lg = lane >> 4;

    __shared__ u16 QL[125][40];
    __shared__ u16 KL[125][40];
    __shared__ u16 VT[32][136];
    __shared__ u16 P[32][136];

    const void* inS = s ? y : x;
    const void* inO = s ? x : y;
    const void* wS  = s ? wqkvy : wqkvx;
    const void* wO  = s ? wqkvx : wqkvy;
    const void* bS  = s ? bqkvy : bqkvx;
    const void* bO  = s ? bqkvx : bqkvy;
    const void* msk = s ? masky : maskx;

    const size_t inb = (size_t)b * (125 * 128);

    #pragma unroll
    for (int t = 0; t < 3; t++) {
        const void* src = t ? inO : inS;
        const void* wp  = t ? wO  : wS;
        const void* bp  = t ? bO  : bS;
        const int wrow = t * 128 + h * 32;

        v8bf bfr[2][4];
        float bv[2];
        #pragma unroll
        for (int nt = 0; nt < 2; nt++) {
            bv[nt] = load1(bp, wrow + nt * 16 + l15, f32);
            #pragma unroll
            for (int kk = 0; kk < 4; kk++)
                bfr[nt][kk] = load8(wp, (size_t)(wrow + nt * 16 + l15) * 128 + kk * 32 + lg * 8, f32);
        }
        #pragma unroll
        for (int mt = 0; mt < 8; mt++) {
            int ar = mt * 16 + l15; if (ar > 124) ar = 124;
            v8bf af[4];
            #pragma unroll
            for (int kk = 0; kk < 4; kk++)
                af[kk] = load8(src, inb + (size_t)ar * 128 + kk * 32 + lg * 8, f32);
            v4f a0 = {0.f,0.f,0.f,0.f}, a1 = {0.f,0.f,0.f,0.f};
            #pragma unroll
            for (int kk = 0; kk < 4; kk++) {
                a0 = MFMA(af[kk], bfr[0][kk], a0);
                a1 = MFMA(af[kk], bfr[1][kk], a1);
            }
            #pragma unroll
            for (int nt = 0; nt < 2; nt++) {
                const v4f acc = nt ? a1 : a0;
                const int col = nt * 16 + l15;
                #pragma unroll
                for (int ri = 0; ri < 4; ri++) {
                    const int wr = mt * 16 + lg * 4 + ri;
                    if (wr < 125) {
                        const u16 val = f2bf(acc[ri] + bv[nt]);
                        if (t == 0)      QL[wr][col] = val;
                        else if (t == 1) KL[wr][col] = val;
                        else             VT[col][wr] = val;
                    }
                }
            }
        }
    }
    for (int z = lane; z < 96; z += 64) VT[z & 31][125 + (z >> 5)] = 0;
    __syncthreads();

    v8bf kf[8];
    #pragma unroll
    for (int jt = 0; jt < 8; jt++) {
        int r = jt * 16 + l15; if (r > 124) r = 124;
        kf[jt] = *(const v8bf*)&KL[r][lg * 8];
    }
    v8bf vf[2][4];
    #pragma unroll
    for (int n2 = 0; n2 < 2; n2++)
        #pragma unroll
        for (int kk = 0; kk < 4; kk++)
            vf[n2][kk] = *(const v8bf*)&VT[n2 * 16 + l15][kk * 32 + lg * 8];

    int cb[8];
    #pragma unroll
    for (int jt = 0; jt < 8; jt++) {
        int col = jt * 16 + l15; if (col > 124) col = 124;
        const int q0 = col / 25, rem = col - q0 * 25, q1 = rem / 5, q2 = rem - q1 * 5;
        cb[jt] = 364 - (q0 * 81 + q1 * 9 + q2);
    }
    const size_t mbase = (size_t)(b & 255) * 15625;
    const float scale = 0.17677669529663689f;
    const v4f z4 = {0.f,0.f,0.f,0.f};

    for (int ch = 0; ch < 4; ch++) {
        v8bf qf[2];
        #pragma unroll
        for (int mt = 0; mt < 2; mt++) {
            int r = ch * 32 + mt * 16 + l15; if (r > 124) r = 124;
            qf[mt] = *(const v8bf*)&QL[r][lg * 8];
        }
        v4f acc[2][8];
        #pragma unroll
        for (int mt = 0; mt < 2; mt++)
            #pragma unroll
            for (int jt = 0; jt < 8; jt++) acc[mt][jt] = z4;
        #pragma unroll
        for (int jt = 0; jt < 8; jt++)
            #pragma unroll
            for (int mt = 0; mt < 2; mt++)
                acc[mt][jt] = MFMA(qf[mt], kf[jt], acc[mt][jt]);

        float rinv[2][4];
        #pragma unroll
        for (int mt = 0; mt < 2; mt++) {
            #pragma unroll
            for (int ri = 0; ri < 4; ri++) {
                const int row = ch * 32 + mt * 16 + lg * 4 + ri;
                const bool rv = row < 125;
                int prow = 0; size_t moff = 0;
                if (rv) {
                    const int p0 = row / 25, rem = row - p0 * 25, p1 = rem / 5, p2 = rem - p1 * 5;
                    prow = p0 * 81 + p1 * 9 + p2;
                    moff = mbase + (size_t)row * 125;
                }
                #pragma unroll
                for (int jt = 0; jt < 8; jt++) {
                    const int col = jt * 16 + l15;
                    float vv = -1e30f;
                    if (rv && col < 125)
                        vv = acc[mt][jt][ri] * scale
                           + load1(rpb, (size_t)(prow + cb[jt]) * 4 + h, f32)
                           + load1(msk, moff + col, f32);
                    acc[mt][jt][ri] = vv;
                }
                float mx = acc[mt][0][ri];
                #pragma unroll
                for (int jt = 1; jt < 8; jt++) mx = fmaxf(mx, acc[mt][jt][ri]);
                mx = fmaxf(mx, __shfl_xor(mx, 1));
                mx = fmaxf(mx, __shfl_xor(mx, 2));
                mx = fmaxf(mx, __shfl_xor(mx, 4));
                mx = fmaxf(mx, __shfl_xor(mx, 8));
                float sum = 0.f;
                #pragma unroll
                for (int jt = 0; jt < 8; jt++) {
                    const float pv = __expf(acc[mt][jt][ri] - mx);
                    acc[mt][jt][ri] = pv; sum += pv;
                }
                sum += __shfl_xor(sum, 1);
                sum += __shfl_xor(sum, 2);
                sum += __shfl_xor(sum, 4);
                sum += __shfl_xor(sum, 8);
                rinv[mt][ri] = 1.0f / sum;
            }
        }

        __syncthreads();
        #pragma unroll
        for (int mt = 0; mt < 2; mt++)
            #pragma unroll
            for (int jt = 0; jt < 8; jt++)
                #pragma unroll
                for (int ri = 0; ri < 4; ri++)
                    P[mt * 16 + lg * 4 + ri][jt * 16 + l15] = f2bf(acc[mt][jt][ri]);
        __syncthreads();

        v4f o[2][2];
        #pragma unroll
        for (int mt = 0; mt < 2; mt++)
            #pragma unroll
            for (int n2 = 0; n2 < 2; n2++) o[mt][n2] = z4;
        #pragma unroll
        for (int mt = 0; mt < 2; mt++) {
            v8bf pa[4];
            #pragma unroll
            for (int kk = 0; kk < 4; kk++)
                pa[kk] = *(const v8bf*)&P[mt * 16 + l15][kk * 32 + lg * 8];
            #pragma unroll
            for (int n2 = 0; n2 < 2; n2++)
                #pragma unroll
                for (int kk = 0; kk < 4; kk++)
                    o[mt][n2] = MFMA(pa[kk], vf[n2][kk], o[mt][n2]);
        }

        #pragma unroll
        for (int mt = 0; mt < 2; mt++)
            #pragma unroll
            for (int n2 = 0; n2 < 2; n2++)
                #pragma unroll
                for (int ri = 0; ri < 4; ri++) {
                    const int row = ch * 32 + mt * 16 + lg * 4 + ri;
                    if (row < 125)
                        out[((size_t)s * 256000 + (size_t)b * 125 + row) * 128
                            + h * 32 + n2 * 16 + l15] = o[mt][n2][ri] * rinv[mt][ri];
                }
    }
}

// ---- output projection, in place on fp32 d_out (shared by both paths) ----
__global__ __launch_bounds__(256) void proj_kernel(
    const void* __restrict__ wpx, const void* __restrict__ bpx,
    const void* __restrict__ wpy, const void* __restrict__ bpy,
    const int* __restrict__ flag, float* io)
{
    const bool f32 = (*flag != 0);
    const int s  = blockIdx.y;
    const int bm = blockIdx.x;
    const void* W    = s ? wpy : wpx;
    const void* bias = s ? bpy : bpx;
    float* A = io + (size_t)s * 32768000;
    const int tid = threadIdx.x, lane = tid & 63, wv = tid >> 6;
    const int l15 = lane & 15, lg = lane >> 4;

    __shared__ u16 Wl[128][136];
    for (int i = tid * 8; i < 16384; i += 2048)
        *(v8bf*)&Wl[i >> 7][i & 127] = load8(W, i, f32);
    __syncthreads();

    const int mbase = bm * 64 + wv * 16;
    v4f acc[8];
    const v4f z4 = {0.f,0.f,0.f,0.f};
    #pragma unroll
    for (int nt = 0; nt < 8; nt++) acc[nt] = z4;

    const float* Ar = A + (size_t)(mbase + l15) * 128;
    v8bf afr[4];
    #pragma unroll
    for (int kk = 0; kk < 4; kk++) {
        union { u16 sI[8]; v8bf v; } U;
        float4 fa = *(const float4*)(Ar + kk * 32 + lg * 8);
        float4 fb = *(const float4*)(Ar + kk * 32 + lg * 8 + 4);
        U.sI[0] = f2bf(fa.x); U.sI[1] = f2bf(fa.y); U.sI[2] = f2bf(fa.z); U.sI[3] = f2bf(fa.w);
        U.sI[4] = f2bf(fb.x); U.sI[5] = f2bf(fb.y); U.sI[6] = f2bf(fb.z); U.sI[7] = f2bf(fb.w);
        afr[kk] = U.v;
    }
    #pragma unroll
    for (int kk = 0; kk < 4; kk++)
        #pragma unroll
        for (int nt = 0; nt < 8; nt++)
            acc[nt] = MFMA(afr[kk], *(const v8bf*)&Wl[nt * 16 + l15][kk * 32 + lg * 8], acc[nt]);

    #pragma unroll
    for (int nt = 0; nt < 8; nt++) {
        const int c = nt * 16 + l15;
        const float bv = load1(bias, c, f32);
        #pragma unroll
        for (int ri = 0; ri < 4; ri++)
            A[(size_t)(mbase + lg * 4 + ri) * 128 + c] = acc[nt][ri] + bv;
    }
}

extern "C" void kernel_launch(void* const* d_in, const int* in_sizes, int n_in,
                              void* d_out, int out_size, void* d_ws, size_t ws_size,
                              hipStream_t stream) {
    const void* x     = d_in[0];
    const void* y     = d_in[1];
    const void* maskx = d_in[2];
    const void* masky = d_in[3];
    const void* wqx   = d_in[4];
    const void* bqx   = d_in[5];
    const void* wqy   = d_in[6];
    const void* bqy   = d_in[7];
    const void* wpx   = d_in[8];
    const void* bpx   = d_in[9];
    const void* wpy   = d_in[10];
    const void* bpy   = d_in[11];
    const void* rpb   = d_in[12];

    // fast-path workspace layout (bytes). Region0 [0, 256000) is time-shared:
    //   phase 1 (qkv): wb [2][384][128] bf16 (196608 B) + bb [2][384] bf16 (1536 B)
    //   phase 2 (attn): rpbT [4][125][128] fp32 (256000 B)  -- written after qkv
    const size_t OFF_R0   = 0;
    const size_t OFF_Q    = 256000;                  // 65.536M bf16 = 131,072,000 B
    const size_t OFF_K    = OFF_Q + 131072000;
    const size_t OFF_VT   = OFF_K + 131072000;       // 67.109M bf16 = 134,217,728 B
    const size_t OFF_FLAG = OFF_VT + 134217728;
    const size_t NEED     = OFF_FLAG + 4;            // 396,617,732 B (same as r4/r5)

    if (ws_size >= NEED) {
        u16*   wb   = (u16*)((char*)d_ws + OFF_R0);
        u16*   bb   = wb + 98304;                    // 196608 B in
        float* rpbT = (float*)((char*)d_ws + OFF_R0);
        u16*   q    = (u16*)((char*)d_ws + OFF_Q);
        u16*   k    = (u16*)((char*)d_ws + OFF_K);
        u16*   vT   = (u16*)((char*)d_ws + OFF_VT);
        int*   flag = (int*)((char*)d_ws + OFF_FLAG);

        probe_kernel<<<1, 64, 0, stream>>>((const unsigned*)x, flag);
        wconv_kernel<<<dim3(192, 2), 256, 0, stream>>>(wqx, bqx, wqy, bqy, flag, wb, bb);
        qkv_kernel<<<dim3(2048, 2), 256, 0, stream>>>(x, y, wb, bb, flag, q, k, vT);
        rpbt_kernel<<<4, 256, 0, stream>>>(rpb, flag, rpbT);     // overwrites wb/bb
        attn_kernel<<<4096, 256, 0, stream>>>(q, k, vT, maskx, masky, rpbT, flag,
                                              (float*)d_out);
        proj_kernel<<<dim3(4000, 2), 256, 0, stream>>>(wpx, bpx, wpy, bpy,
                                                       flag, (float*)d_out);
    } else {
        int* flag = (int*)d_ws;
        probe_kernel<<<1, 64, 0, stream>>>((const unsigned*)x, flag);
        fused_attn<<<dim3(4096, 4), 64, 0, stream>>>(x, y, maskx, masky,
                                                     wqx, bqx, wqy, bqy,
                                                     rpb, flag, (float*)d_out);
        proj_kernel<<<dim3(4000, 2), 256, 0, stream>>>(wpx, bpx, wpy, bpy,
                                                       flag, (float*)d_out);
    }
}